// Round 9
// baseline (37041.177 us; speedup 1.0000x reference)
//
#include <hip/hip_runtime.h>
#include <math.h>

#define LSEQ 512
#define BATCH 64
#define HID 1024
#define NCH 8
#define GSZ 4112
#define NBLK 64

typedef __bf16 bf16x8 __attribute__((ext_vector_type(8)));
typedef float f32x4 __attribute__((ext_vector_type(4)));
typedef unsigned u32x4 __attribute__((ext_vector_type(4)));

__device__ __forceinline__ ushort f2b(float f) {
  union { float f; unsigned u; } v; v.f = f;
  unsigned u = v.u;
  unsigned r = (u + 0x7FFFu + ((u >> 16) & 1u)) >> 16;  // RNE
  return (ushort)r;
}
__device__ __forceinline__ float b2f(ushort h) {
  union { unsigned u; float f; } v; v.u = (unsigned)h << 16; return v.f;
}
__device__ __forceinline__ float sigmoidf(float x) { return 1.f / (1.f + expf(-x)); }

// ---- transpose + cast: W (K x N) f32 -> WT (N x K) bf16 ----
__global__ __launch_bounds__(256) void k_transpose_cast(
    const float* __restrict__ W, ushort* __restrict__ WT, int K, int N) {
  __shared__ float tile[32][33];
  int n0 = blockIdx.x * 32, k0 = blockIdx.y * 32;
  int tx = threadIdx.x & 31, ty = threadIdx.x >> 5;
  #pragma unroll
  for (int i = ty; i < 32; i += 8) {
    int n = n0 + tx;
    tile[i][tx] = (n < N) ? W[(size_t)(k0 + i) * N + n] : 0.f;
  }
  __syncthreads();
  #pragma unroll
  for (int i = ty; i < 32; i += 8) {
    int n = n0 + i;
    if (n < N) WT[(size_t)n * K + k0 + tx] = f2b(tile[tx][i]);
  }
}

// ---- f32 -> bf16 cast (vectorized x4) ----
__global__ void k_cast4(const float4* __restrict__ in, ushort* __restrict__ out, int count4) {
  int stride = gridDim.x * blockDim.x;
  for (int i = blockIdx.x * blockDim.x + threadIdx.x; i < count4; i += stride) {
    float4 v = in[i];
    ushort4 o;
    o.x = f2b(v.x); o.y = f2b(v.y); o.z = f2b(v.z); o.w = f2b(v.w);
    *reinterpret_cast<ushort4*>(out + (size_t)i * 4) = o;
  }
}

__global__ void k_init_state(const float* __restrict__ h0l, const float* __restrict__ c0l,
                             ushort* __restrict__ hb, float* __restrict__ c,
                             unsigned* __restrict__ barmem, int count) {
  int i = blockIdx.x * blockDim.x + threadIdx.x;
  if (i < count) { hb[i] = f2b(h0l[i]); c[i] = c0l[i]; }
  if (i < NBLK * 16) barmem[i] = 0u;  // per-block flag cachelines
}

// Ct[t][col][batch] (bf16) = A[t*64+b][K](bf16) @ BT[col][K](bf16)^T + bias[col]
__global__ __launch_bounds__(256) void k_gemm_t(
    const ushort* __restrict__ A, const ushort* __restrict__ BT,
    const float* __restrict__ bias, ushort* __restrict__ Ct, int K, int N) {
  int col0 = blockIdx.x * 64;
  int t = blockIdx.y;
  int lane = threadIdx.x & 63;
  int w = threadIdx.x >> 6;
  int l15 = lane & 15;
  int koff = (lane >> 4) * 8;
  const ushort* Ap = A + (size_t)(t * 64 + w * 16 + l15) * K + koff;
  const ushort* Bp[4];
  int cols[4];
  #pragma unroll
  for (int cg = 0; cg < 4; ++cg) {
    int c_ = col0 + cg * 16 + l15;
    cols[cg] = c_;
    int cc = c_ < N ? c_ : N - 1;  // clamp reads on partial tile
    Bp[cg] = BT + (size_t)cc * K + koff;
  }
  f32x4 acc[4] = {};
  #pragma unroll 4
  for (int kk = 0; kk < K; kk += 32) {
    bf16x8 a = *reinterpret_cast<const bf16x8*>(Ap + kk);
    #pragma unroll
    for (int cg = 0; cg < 4; ++cg) {
      bf16x8 b = *reinterpret_cast<const bf16x8*>(Bp[cg] + kk);
      acc[cg] = __builtin_amdgcn_mfma_f32_16x16x32_bf16(a, b, acc[cg], 0, 0, 0);
    }
  }
  int crow = w * 16 + (lane >> 4) * 4;  // batch row base
  #pragma unroll
  for (int cg = 0; cg < 4; ++cg) {
    int c_ = cols[cg];
    if (c_ >= N) continue;
    float bv = bias[c_];
    ushort4 o;
    o.x = f2b(acc[cg][0] + bv); o.y = f2b(acc[cg][1] + bv);
    o.z = f2b(acc[cg][2] + bv); o.w = f2b(acc[cg][3] + bv);
    *reinterpret_cast<ushort4*>(&Ct[((size_t)t * GSZ + c_) * 64 + crow]) = o;
  }
}

// ---- persistent scan: 64 blocks x 1024 threads, 4 INDEPENDENT groups ----
// Batch rows are independent through the recurrence. Group g (blocks g*16 ..
// g*16+15) owns batch rows [16g,16g+16). Block (g,i) owns hid slice
// [64i,64i+64): computes softmax cols 0..15 (redundant) + its 4x64 gate cols,
// and the cell for its 16x64 (batch,hid) patch. h exchange = 32 KB via LLC
// (sc0 sc1); barrier = 16 per-block flags per group (load-polled, no atomics,
// no L2 flush). Groups never sync with each other.
__global__ __launch_bounds__(1024, 4) void k_scan(
    const ushort* __restrict__ WhhT,  // [GSZ][HID] bf16
    const float* __restrict__ bhh,
    const ushort* __restrict__ tin,   // [nsteps][GSZ][64] bf16
    ushort* __restrict__ hbuf0, ushort* __restrict__ hbuf1,  // [64][1024] bf16
    float* __restrict__ cws,          // [64][1024] f32
    float* __restrict__ out_hs, float* __restrict__ out_hs2,
    float* __restrict__ dfs, float* __restrict__ dins,
    float* __restrict__ hT, float* __restrict__ cT,
    unsigned* __restrict__ barmem, int nsteps, int barbase) {
  __shared__ ushort hlds[16 * 1024];   // 32 KB: group h, XOR-swizzled
  __shared__ float gbuf[272][17];      // [gate col][batch]; odd pad -> 2-way max

  const int tid = threadIdx.x;
  const int blk = blockIdx.x;
  const int g = blk >> 4;       // batch group 0..3
  const int i = blk & 15;       // hid/col slice 0..15
  const int lane = tid & 63;
  const int w = tid >> 6;       // wave 0..15
  const int l15 = lane & 15;
  const int lg = lane >> 4;     // lane group 0..3

  // GEMM wave constants: wave w -> gate kind q, col sub-tile s
  const int q = w >> 2, s = w & 3;
  const int gcol = 16 + q * 1024 + i * 64 + s * 16 + l15;
  const ushort* bp = WhhT + (size_t)gcol * HID + lg * 8;
  const float bv = bhh[gcol];
  const int growo = 16 + q * 64 + s * 16 + l15;  // gbuf row
  const int crow = lg * 4;                        // batch row base in tile
  const unsigned ab = (unsigned)l15 * 2048u + (unsigned)(lg * 16);
  const unsigned swz = (unsigned)(l15 & 7) << 4;
  // softmax tile (wave 0 only)
  const ushort* sp = WhhT + (size_t)l15 * HID + lg * 8;
  const float bvs = bhh[l15];

  // h staging addresses (2 x 16B per thread)
  const unsigned hoff0 = (unsigned)tid * 16u;
  const unsigned hoff1 = hoff0 + 16384u;
  const unsigned wb0 = hoff0 ^ (((hoff0 >> 11) & 7u) << 4);
  const unsigned wb1 = hoff1 ^ (((hoff1 >> 11) & 7u) << 4);

  // cell mapping: wave = batch row, lane = hid within slice
  const int cb = tid >> 6;          // batch row in group
  const int jl = tid & 63;          // hid in slice
  const int jglob = i * 64 + jl;
  const int bglob = g * 16 + cb;
  const int r = jglob >> 7;
  float creg = cws[bglob * HID + jglob];

  float def_hy = 0.f, def_df = 0.f, def_di = 0.f;
  size_t def_oidx = 0;

  for (int tt = 0; tt < nsteps; ++tt) {
    // ---- stage group h (LLC-coherent) -> LDS, swizzled ----
    const char* hb = (const char*)((tt & 1) ? hbuf1 : hbuf0) + (size_t)g * 32768;
    u32x4 v0, v1;
    asm volatile("global_load_dwordx4 %0, %1, off sc0 sc1"
                 : "=v"(v0) : "v"(hb + hoff0) : "memory");
    asm volatile("global_load_dwordx4 %0, %1, off sc0 sc1"
                 : "=v"(v1) : "v"(hb + hoff1) : "memory");
    asm volatile("s_waitcnt vmcnt(0)" ::: "memory");
    __builtin_amdgcn_sched_barrier(0);
    *(u32x4*)((char*)hlds + wb0) = v0;
    *(u32x4*)((char*)hlds + wb1) = v1;

    // deferred output stores from step tt-1 (complete during GEMM)
    if (tt > 0) {
      out_hs[def_oidx] = def_hy;
      if (out_hs2) out_hs2[def_oidx] = def_hy;
      if (i == 0 && jl == 0) {
        dfs[(tt - 1) * BATCH + bglob] = def_df;
        dins[(tt - 1) * BATCH + bglob] = def_di;
      }
    }
    __syncthreads();

    // ---- GEMM: own tile (all waves), softmax tile (wave 0) ----
    {
      const ushort* tp = tin + ((size_t)tt * GSZ + gcol) * 64 + g * 16 + crow;
      ushort4 tv = *(const ushort4*)tp;
      f32x4 aA = {}, aB = {};
      #pragma unroll
      for (int kb = 0; kb < 32; kb += 2) {
        bf16x8 b0 = *(const bf16x8*)(bp + kb * 32);
        bf16x8 b1 = *(const bf16x8*)(bp + kb * 32 + 32);
        bf16x8 x0 = *(const bf16x8*)((const char*)hlds + ((ab + (unsigned)kb * 64u) ^ swz));
        bf16x8 x1 = *(const bf16x8*)((const char*)hlds + ((ab + (unsigned)kb * 64u + 64u) ^ swz));
        aA = __builtin_amdgcn_mfma_f32_16x16x32_bf16(x0, b0, aA, 0, 0, 0);
        aB = __builtin_amdgcn_mfma_f32_16x16x32_bf16(x1, b1, aB, 0, 0, 0);
      }
      gbuf[growo][crow + 0] = aA[0] + aB[0] + bv + b2f(tv.x);
      gbuf[growo][crow + 1] = aA[1] + aB[1] + bv + b2f(tv.y);
      gbuf[growo][crow + 2] = aA[2] + aB[2] + bv + b2f(tv.z);
      gbuf[growo][crow + 3] = aA[3] + aB[3] + bv + b2f(tv.w);
    }
    if (w == 0) {
      const ushort* tp = tin + ((size_t)tt * GSZ + l15) * 64 + g * 16 + crow;
      ushort4 tv = *(const ushort4*)tp;
      f32x4 aA = {}, aB = {};
      #pragma unroll
      for (int kb = 0; kb < 32; kb += 2) {
        bf16x8 b0 = *(const bf16x8*)(sp + kb * 32);
        bf16x8 b1 = *(const bf16x8*)(sp + kb * 32 + 32);
        bf16x8 x0 = *(const bf16x8*)((const char*)hlds + ((ab + (unsigned)kb * 64u) ^ swz));
        bf16x8 x1 = *(const bf16x8*)((const char*)hlds + ((ab + (unsigned)kb * 64u + 64u) ^ swz));
        aA = __builtin_amdgcn_mfma_f32_16x16x32_bf16(x0, b0, aA, 0, 0, 0);
        aB = __builtin_amdgcn_mfma_f32_16x16x32_bf16(x1, b1, aB, 0, 0, 0);
      }
      gbuf[l15][crow + 0] = aA[0] + aB[0] + bvs + b2f(tv.x);
      gbuf[l15][crow + 1] = aA[1] + aB[1] + bvs + b2f(tv.y);
      gbuf[l15][crow + 2] = aA[2] + aB[2] + bvs + b2f(tv.z);
      gbuf[l15][crow + 3] = aA[3] + aB[3] + bvs + b2f(tv.w);
    }
    __syncthreads();

    // ---- fused cell update ----
    float sm0[NCH], sm1[NCH];
    float m1 = -1e30f, m2 = -1e30f;
    #pragma unroll
    for (int k = 0; k < NCH; ++k) {
      sm0[k] = gbuf[k][cb];          // wave-uniform -> broadcast
      sm1[k] = gbuf[NCH + k][cb];
      m1 = fmaxf(m1, sm0[k]);
      m2 = fmaxf(m2, sm1[k]);
    }
    float s1 = 0.f, s2 = 0.f;
    #pragma unroll
    for (int k = 0; k < NCH; ++k) {
      sm0[k] = expf(sm0[k] - m1); s1 += sm0[k];
      sm1[k] = expf(sm1[k] - m2); s2 += sm1[k];
    }
    float r1 = 1.f / s1, r2 = 1.f / s2;
    float cum1 = 0.f, cum2 = 0.f, sumin = 0.f, sumfg = 0.f;
    float cing[NCH], cfg[NCH];
    #pragma unroll
    for (int k = 0; k < NCH; ++k) {
      cum1 += sm0[k] * r1; cing[k] = 1.f - cum1; sumin += cing[k];
      cum2 += sm1[k] * r2; cfg[k] = cum2; sumfg += cfg[k];
    }
    float go = gbuf[16 + jl][cb];
    float gc = gbuf[80 + jl][cb];
    float gi = gbuf[144 + jl][cb];
    float gf = gbuf[208 + jl][cb];
    float ov = cfg[r] * cing[r];
    float f_ = sigmoidf(gf) * ov + (cfg[r] - ov);
    float i_ = sigmoidf(gi) * ov + (cing[r] - ov);
    float cy = f_ * creg + i_ * tanhf(gc);
    float hy = sigmoidf(go) * tanhf(cy);
    creg = cy;

    // ---- h store: write-through to LLC, packed bf16 pairs ----
    ushort hv = f2b(hy);
    unsigned other = (unsigned)__shfl_xor((int)(unsigned)hv, 1, 64);
    ushort* hw = ((tt & 1) ? hbuf0 : hbuf1) + bglob * HID + jglob;
    if ((jl & 1) == 0) {
      unsigned pk = (unsigned)hv | (other << 16);
      asm volatile("global_store_dword %0, %1, off sc0 sc1" :: "v"(hw), "v"(pk) : "memory");
    }
    if (hT && tt == nsteps - 1) {
      hT[bglob * HID + jglob] = hy;
      cT[bglob * HID + jglob] = cy;
    }

    // defer bulk output stores to next iteration
    def_hy = hy;
    def_oidx = ((size_t)tt * BATCH + bglob) * HID + jglob;
    def_df = 1.f - sumfg * 0.125f;
    def_di = sumin * 0.125f;

    // ---- per-group flag barrier (16 flags), load-polled ----
    if (tt < nsteps - 1) {
      asm volatile("s_waitcnt vmcnt(0)" ::: "memory");  // h store at LLC
      __syncthreads();
      if (w == 0) {
        unsigned tgt = (unsigned)(barbase + tt + 1);
        if (lane == 0) {
          unsigned* fp = barmem + (unsigned)blk * 16u;
          asm volatile("global_store_dword %0, %1, off sc0 sc1"
                       :: "v"(fp), "v"(tgt) : "memory");
        }
        const unsigned* mp = barmem + (unsigned)(g * 16 + l15) * 16u;
        while (true) {
          unsigned f;
          asm volatile("global_load_dword %0, %1, off sc0 sc1"
                       : "=v"(f) : "v"(mp) : "memory");
          asm volatile("s_waitcnt vmcnt(0)" ::: "memory");
          if (__all((int)(f >= tgt))) break;
          __builtin_amdgcn_s_sleep(1);
        }
      }
      __syncthreads();
    }
  }
  // flush deferred stores of the last step
  out_hs[def_oidx] = def_hy;
  if (out_hs2) out_hs2[def_oidx] = def_hy;
  if (i == 0 && jl == 0) {
    dfs[(nsteps - 1) * BATCH + bglob] = def_df;
    dins[(nsteps - 1) * BATCH + bglob] = def_di;
  }
  cws[bglob * HID + jglob] = creg;
}

extern "C" void kernel_launch(void* const* d_in, const int* in_sizes, int n_in,
                              void* d_out, int out_size, void* d_ws, size_t ws_size,
                              hipStream_t stream) {
  const float* x   = (const float*)d_in[0];
  const float* h0  = (const float*)d_in[1];
  const float* c0  = (const float*)d_in[2];
  const float* Wih = (const float*)d_in[3];
  const float* bih = (const float*)d_in[4];
  const float* Whh = (const float*)d_in[5];
  const float* bhh = (const float*)d_in[6];
  float* out = (float*)d_out;

  const size_t OFF_OUTPUT = 0;                  // (512,64,1024)
  const size_t OFF_HT   = 33554432;             // (2,64,1024)
  const size_t OFF_CT   = OFF_HT + 131072;      // (2,64,8,128)
  const size_t OFF_OUTS = OFF_CT + 131072;      // (2,512,64,1024)
  const size_t OFF_DFS  = OFF_OUTS + 67108864;  // (2,512,64)
  const size_t OFF_DINS = OFF_DFS + 65536;      // (2,512,64)

  uint8_t* ws = (uint8_t*)d_ws;
  size_t off = 0;
  auto alloc = [&](size_t bytes) { size_t p = off; off = (off + bytes + 255) & ~(size_t)255; return p; };
  const size_t wT_sz = (size_t)GSZ * HID * 2;
  size_t o_WihT[2], o_WhhT[2];
  o_WihT[0] = alloc(wT_sz); o_WihT[1] = alloc(wT_sz);
  o_WhhT[0] = alloc(wT_sz); o_WhhT[1] = alloc(wT_sz);
  size_t o_h0b = alloc((size_t)BATCH * HID * 2);
  size_t o_h1b = alloc((size_t)BATCH * HID * 2);
  size_t o_c   = alloc((size_t)BATCH * HID * 4);
  size_t o_bar = alloc(4096);
  size_t fixed = off;
  const size_t unit = (size_t)BATCH * HID * 2 + (size_t)BATCH * GSZ * 2 + 512;
  int TC = 256;
  while (TC > 2 && fixed + (size_t)TC * unit > ws_size) TC >>= 1;
  size_t o_prevb = alloc((size_t)TC * BATCH * HID * 2);
  size_t o_tin   = alloc((size_t)TC * BATCH * GSZ * 2);

  ushort* hb0 = (ushort*)(ws + o_h0b);
  ushort* hb1 = (ushort*)(ws + o_h1b);
  float*  cst = (float*)(ws + o_c);
  unsigned* barmem = (unsigned*)(ws + o_bar);
  ushort* prevb = (ushort*)(ws + o_prevb);
  ushort* tin   = (ushort*)(ws + o_tin);

  dim3 tgrid((GSZ + 31) / 32, HID / 32);
  for (int l = 0; l < 2; ++l) {
    k_transpose_cast<<<tgrid, 256, 0, stream>>>(Wih + (size_t)l * HID * GSZ,
                                                (ushort*)(ws + o_WihT[l]), HID, GSZ);
    k_transpose_cast<<<tgrid, 256, 0, stream>>>(Whh + (size_t)l * HID * GSZ,
                                                (ushort*)(ws + o_WhhT[l]), HID, GSZ);
  }

  const int NB = (GSZ + 63) / 64;
  for (int l = 0; l < 2; ++l) {
    const float* prev = (l == 0) ? x : (out + OFF_OUTS);  // layer-0 hs in outs[0]
    const ushort* WihT = (const ushort*)(ws + o_WihT[l]);

    k_init_state<<<256, 256, 0, stream>>>(h0 + (size_t)l * BATCH * HID,
                                          c0 + (size_t)l * BATCH * HID,
                                          hb0, cst, barmem, BATCH * HID);

    int barbase = 0;  // cumulative barrier rounds this layer
    for (int t0 = 0; t0 < LSEQ; t0 += TC) {
      int nsteps = (LSEQ - t0 < TC) ? (LSEQ - t0) : TC;

      int count4 = nsteps * BATCH * HID / 4;
      int cblocks = (count4 + 255) / 256; if (cblocks > 2048) cblocks = 2048;
      k_cast4<<<cblocks, 256, 0, stream>>>(
          (const float4*)(prev + (size_t)t0 * BATCH * HID), prevb, count4);

      k_gemm_t<<<dim3(NB, nsteps), 256, 0, stream>>>(prevb, WihT,
                                                     bih + (size_t)l * GSZ, tin, HID, GSZ);

      bool last = (t0 + nsteps == LSEQ);
      const ushort* WhhT_p = (const ushort*)(ws + o_WhhT[l]);
      const float* bhh_p = bhh + (size_t)l * GSZ;
      const ushort* tin_p = tin;
      ushort* h0_p = hb0;
      ushort* h1_p = hb1;
      float* c_p = cst;
      float* ohs  = out + OFF_OUTS + ((size_t)l * LSEQ + t0) * BATCH * HID;
      float* ohs2 = (l == 1) ? (out + OFF_OUTPUT + (size_t)t0 * BATCH * HID) : nullptr;
      float* dfsp  = out + OFF_DFS  + ((size_t)l * LSEQ + t0) * BATCH;
      float* dinsp = out + OFF_DINS + ((size_t)l * LSEQ + t0) * BATCH;
      float* hTp = last ? (out + OFF_HT + (size_t)l * BATCH * HID) : nullptr;
      float* cTp = last ? (out + OFF_CT + (size_t)l * BATCH * HID) : nullptr;
      int nsteps_v = nsteps;
      int barbase_v = barbase;

      void* args[] = {&WhhT_p, &bhh_p, &tin_p, &h0_p, &h1_p, &c_p, &ohs, &ohs2,
                      &dfsp, &dinsp, &hTp, &cTp, &barmem, &nsteps_v, &barbase_v};
      hipLaunchCooperativeKernel((const void*)k_scan, dim3(NBLK), dim3(1024),
                                 args, 0, stream);
      barbase += nsteps - 1;

      // h parity: if nsteps is odd the final h landed in the "other" buffer
      if (nsteps & 1) { ushort* tmp = hb0; hb0 = hb1; hb1 = tmp; }
    }
  }
}

// Round 10
// 20352.742 us; speedup vs baseline: 1.8200x; 1.8200x over previous
//
#include <hip/hip_runtime.h>
#include <math.h>

#define LSEQ 512
#define BATCH 64
#define HID 1024
#define NCH 8
#define GSZ 4112
#define NBLK 64

typedef __bf16 bf16x8 __attribute__((ext_vector_type(8)));
typedef float f32x4 __attribute__((ext_vector_type(4)));
typedef unsigned u32x4 __attribute__((ext_vector_type(4)));

__device__ __forceinline__ ushort f2b(float f) {
  union { float f; unsigned u; } v; v.f = f;
  unsigned u = v.u;
  unsigned r = (u + 0x7FFFu + ((u >> 16) & 1u)) >> 16;  // RNE
  return (ushort)r;
}
__device__ __forceinline__ float b2f(ushort h) {
  union { unsigned u; float f; } v; v.u = (unsigned)h << 16; return v.f;
}
__device__ __forceinline__ float sigmoidf(float x) { return 1.f / (1.f + expf(-x)); }

// ---- transpose + cast: W (K x N) f32 -> WT (N x K) bf16 ----
__global__ __launch_bounds__(256) void k_transpose_cast(
    const float* __restrict__ W, ushort* __restrict__ WT, int K, int N) {
  __shared__ float tile[32][33];
  int n0 = blockIdx.x * 32, k0 = blockIdx.y * 32;
  int tx = threadIdx.x & 31, ty = threadIdx.x >> 5;
  #pragma unroll
  for (int i = ty; i < 32; i += 8) {
    int n = n0 + tx;
    tile[i][tx] = (n < N) ? W[(size_t)(k0 + i) * N + n] : 0.f;
  }
  __syncthreads();
  #pragma unroll
  for (int i = ty; i < 32; i += 8) {
    int n = n0 + i;
    if (n < N) WT[(size_t)n * K + k0 + tx] = f2b(tile[tx][i]);
  }
}

// ---- f32 -> bf16 cast (vectorized x4) ----
__global__ void k_cast4(const float4* __restrict__ in, ushort* __restrict__ out, int count4) {
  int stride = gridDim.x * blockDim.x;
  for (int i = blockIdx.x * blockDim.x + threadIdx.x; i < count4; i += stride) {
    float4 v = in[i];
    ushort4 o;
    o.x = f2b(v.x); o.y = f2b(v.y); o.z = f2b(v.z); o.w = f2b(v.w);
    *reinterpret_cast<ushort4*>(out + (size_t)i * 4) = o;
  }
}

__global__ void k_init_state(const float* __restrict__ h0l, const float* __restrict__ c0l,
                             ushort* __restrict__ hb, float* __restrict__ c,
                             unsigned* __restrict__ barmem, int count) {
  int i = blockIdx.x * blockDim.x + threadIdx.x;
  if (i < count) { hb[i] = f2b(h0l[i]); c[i] = c0l[i]; }
  if (i < NBLK * 16) barmem[i] = 0u;  // per-block flag cachelines
}

// Ct[t][col][batch] (bf16) = A[t*64+b][K](bf16) @ BT[col][K](bf16)^T + bias[col]
__global__ __launch_bounds__(256) void k_gemm_t(
    const ushort* __restrict__ A, const ushort* __restrict__ BT,
    const float* __restrict__ bias, ushort* __restrict__ Ct, int K, int N) {
  int col0 = blockIdx.x * 64;
  int t = blockIdx.y;
  int lane = threadIdx.x & 63;
  int w = threadIdx.x >> 6;
  int l15 = lane & 15;
  int koff = (lane >> 4) * 8;
  const ushort* Ap = A + (size_t)(t * 64 + w * 16 + l15) * K + koff;
  const ushort* Bp[4];
  int cols[4];
  #pragma unroll
  for (int cg = 0; cg < 4; ++cg) {
    int c_ = col0 + cg * 16 + l15;
    cols[cg] = c_;
    int cc = c_ < N ? c_ : N - 1;  // clamp reads on partial tile
    Bp[cg] = BT + (size_t)cc * K + koff;
  }
  f32x4 acc[4] = {};
  #pragma unroll 4
  for (int kk = 0; kk < K; kk += 32) {
    bf16x8 a = *reinterpret_cast<const bf16x8*>(Ap + kk);
    #pragma unroll
    for (int cg = 0; cg < 4; ++cg) {
      bf16x8 b = *reinterpret_cast<const bf16x8*>(Bp[cg] + kk);
      acc[cg] = __builtin_amdgcn_mfma_f32_16x16x32_bf16(a, b, acc[cg], 0, 0, 0);
    }
  }
  int crow = w * 16 + (lane >> 4) * 4;  // batch row base
  #pragma unroll
  for (int cg = 0; cg < 4; ++cg) {
    int c_ = cols[cg];
    if (c_ >= N) continue;
    float bv = bias[c_];
    ushort4 o;
    o.x = f2b(acc[cg][0] + bv); o.y = f2b(acc[cg][1] + bv);
    o.z = f2b(acc[cg][2] + bv); o.w = f2b(acc[cg][3] + bv);
    *reinterpret_cast<ushort4*>(&Ct[((size_t)t * GSZ + c_) * 64 + crow]) = o;
  }
}

// ---- persistent scan: 64 blocks x 1024 threads (16 waves), FULL sync ----
// Round-8 structure with balanced GEMM: 10 GEMM waves, wave w -> col-tile
// ct=w>>1 (0=softmax, 1..4=out/cell/in/fg), batch half = w&1 (32 rows = 2
// M16 tiles). Critical path = 64 MFMA per wave (4x shorter than round 8's
// wave 0). tin double-buffered in registers: step t+1's tin issued right
// after step t's epilogue (~8us of latency cover). Barrier: per-block flag
// cachelines + 64-lane gather poll (no atomics, no L2 flush).
__global__ __launch_bounds__(1024, 4) void k_scan(
    const ushort* __restrict__ WhhT,  // [GSZ][HID] bf16
    const float* __restrict__ bhh,
    const ushort* __restrict__ tin,   // [nsteps][GSZ][64] bf16
    ushort* __restrict__ hbuf0, ushort* __restrict__ hbuf1,  // [64][1024] bf16
    float* __restrict__ cws,          // [64][1024] f32
    float* __restrict__ out_hs, float* __restrict__ out_hs2,
    float* __restrict__ dfs, float* __restrict__ dins,
    float* __restrict__ hT, float* __restrict__ cT,
    unsigned* __restrict__ barmem, int nsteps, int barbase) {
  __shared__ unsigned hlds[32768];              // 128 KB: h staged, XOR-swizzled
  __shared__ __align__(16) float gbuf[80][68];  // [gate col][batch]

  const int tid = threadIdx.x;
  const int blk = blockIdx.x;
  const int j0 = blk * 16;
  const int lane = tid & 63;
  const int w = tid >> 6;       // wave 0..15
  const int l15 = lane & 15;
  const int lg = lane >> 4;     // 0..3 (k-slot for A/B frags, batch sub-row)
  const int koff = lg * 8;

  // GEMM-wave constants (w < 10): col-tile ct, batch half
  const int ct = (w < 10) ? (w >> 1) : 0;
  const int half = w & 1;
  const int gcol = (ct == 0) ? l15 : (16 + (ct - 1) * 1024 + j0 + l15);
  const int grow = (ct == 0) ? l15 : (16 + (ct - 1) * 16 + l15);
  const ushort* bp = WhhT + (size_t)gcol * HID + koff;
  const float bv = bhh[gcol];
  const int cr = lg * 4;                      // batch sub-row base in M16 tile
  const int b0 = half * 32;                   // batch base for this wave
  // A-frag LDS byte offsets for the two M16 tiles (rows b0+l15, b0+16+l15)
  const unsigned ab0 = (unsigned)(b0 + l15) * 2048u + (unsigned)koff * 2u;
  const unsigned ab1 = ab0 + 32768u;
  const unsigned swz = (unsigned)(l15 & 7) << 4;
  const ushort* tinw = tin + (size_t)gcol * 64 + b0 + cr;  // + tt*GSZ*64

  // cell mapping: thread -> (batch cb, local hidden jl)
  const int cb = tid >> 4;
  const int jl = tid & 15;
  const int jglob = j0 + jl;
  const int r = jglob >> 7;
  float creg = cws[cb * HID + jglob];

  float def_hy = 0.f, def_df = 0.f, def_di = 0.f;
  size_t def_oidx = 0;

  // prefetch tin for step 0 (two ushort4 per GEMM wave: batch cr, cr+16)
  ushort4 tvA = {0,0,0,0}, tvB = {0,0,0,0};
  if (w < 10) {
    tvA = *(const ushort4*)(tinw);
    tvB = *(const ushort4*)(tinw + 16);
  }

  for (int tt = 0; tt < nsteps; ++tt) {
    // ---- deferred output stores from step tt-1 (off critical path) ----
    if (tt > 0) {
      out_hs[def_oidx] = def_hy;
      if (out_hs2) out_hs2[def_oidx] = def_hy;
      if (blk == 0 && jl == 0) {
        dfs[(tt - 1) * BATCH + cb] = def_df;
        dins[(tt - 1) * BATCH + cb] = def_di;
      }
    }

    // ---- stage h (coherent LLC read) -> LDS, swizzled ----
    const u32x4* hs = (const u32x4*)((tt & 1) ? hbuf1 : hbuf0);
    u32x4 v0, v1, v2, v3, v4, v5, v6, v7;
#define CLOAD(dst, I) asm volatile("global_load_dwordx4 %0, %1, off sc0 sc1" \
      : "=v"(dst) : "v"(hs + tid + (I)*1024) : "memory")
    CLOAD(v0, 0); CLOAD(v1, 1); CLOAD(v2, 2); CLOAD(v3, 3);
    CLOAD(v4, 4); CLOAD(v5, 5); CLOAD(v6, 6); CLOAD(v7, 7);
#undef CLOAD
    asm volatile("s_waitcnt vmcnt(0)" ::: "memory");
    __builtin_amdgcn_sched_barrier(0);
#define WST(v, I) { unsigned byte_ = (unsigned)(tid + (I)*1024) * 16u; \
    unsigned row_ = byte_ >> 11; \
    *(u32x4*)((char*)hlds + (byte_ ^ ((row_ & 7u) << 4))) = v; }
    WST(v0, 0); WST(v1, 1); WST(v2, 2); WST(v3, 3);
    WST(v4, 4); WST(v5, 5); WST(v6, 6); WST(v7, 7);
#undef WST
    __syncthreads();

    // ---- GEMM: 10 waves, 1 col-tile x 2 M16 batch tiles each ----
    if (w < 10) {
      f32x4 aA = {}, aB = {};
      #pragma unroll 8
      for (int kb = 0; kb < 32; ++kb) {
        bf16x8 b = *(const bf16x8*)(bp + kb * 32);
        unsigned o = (unsigned)kb * 64u;
        bf16x8 x0 = *(const bf16x8*)((const char*)hlds + ((ab0 + o) ^ swz));
        bf16x8 x1 = *(const bf16x8*)((const char*)hlds + ((ab1 + o) ^ swz));
        aA = __builtin_amdgcn_mfma_f32_16x16x32_bf16(x0, b, aA, 0, 0, 0);
        aB = __builtin_amdgcn_mfma_f32_16x16x32_bf16(x1, b, aB, 0, 0, 0);
      }
      f32x4 g;
      g[0] = aA[0] + bv + b2f(tvA.x); g[1] = aA[1] + bv + b2f(tvA.y);
      g[2] = aA[2] + bv + b2f(tvA.z); g[3] = aA[3] + bv + b2f(tvA.w);
      *(f32x4*)(&gbuf[grow][b0 + cr]) = g;
      g[0] = aB[0] + bv + b2f(tvB.x); g[1] = aB[1] + bv + b2f(tvB.y);
      g[2] = aB[2] + bv + b2f(tvB.z); g[3] = aB[3] + bv + b2f(tvB.w);
      *(f32x4*)(&gbuf[grow][b0 + 16 + cr]) = g;
      // issue next step's tin now: completes during cell+barrier+h-stage
      if (tt + 1 < nsteps) {
        const ushort* tp = tinw + (size_t)(tt + 1) * GSZ * 64;
        tvA = *(const ushort4*)(tp);
        tvB = *(const ushort4*)(tp + 16);
      }
    }
    __syncthreads();

    // ---- fused cell update (all 1024 threads) ----
    float sm0[NCH], sm1[NCH];
    float m1 = -1e30f, m2 = -1e30f;
    #pragma unroll
    for (int i = 0; i < NCH; ++i) {
      sm0[i] = gbuf[i][cb];
      sm1[i] = gbuf[NCH + i][cb];
      m1 = fmaxf(m1, sm0[i]);
      m2 = fmaxf(m2, sm1[i]);
    }
    float s1 = 0.f, s2 = 0.f;
    #pragma unroll
    for (int i = 0; i < NCH; ++i) {
      sm0[i] = expf(sm0[i] - m1); s1 += sm0[i];
      sm1[i] = expf(sm1[i] - m2); s2 += sm1[i];
    }
    float r1 = 1.f / s1, r2 = 1.f / s2;
    float cum1 = 0.f, cum2 = 0.f, sumin = 0.f, sumfg = 0.f;
    float cing[NCH], cfg[NCH];
    #pragma unroll
    for (int i = 0; i < NCH; ++i) {
      cum1 += sm0[i] * r1; cing[i] = 1.f - cum1; sumin += cing[i];
      cum2 += sm1[i] * r2; cfg[i] = cum2; sumfg += cfg[i];
    }
    float go = gbuf[16 + jl][cb];
    float gc = gbuf[32 + jl][cb];
    float gi = gbuf[48 + jl][cb];
    float gf = gbuf[64 + jl][cb];
    float ov = cfg[r] * cing[r];
    float f_ = sigmoidf(gf) * ov + (cfg[r] - ov);
    float i_ = sigmoidf(gi) * ov + (cing[r] - ov);
    float cy = f_ * creg + i_ * tanhf(gc);
    float hy = sigmoidf(go) * tanhf(cy);
    creg = cy;

    // ---- h store: write-through to LLC, packed bf16 pairs ----
    ushort hv = f2b(hy);
    unsigned other = (unsigned)__shfl_xor((int)(unsigned)hv, 1, 64);
    ushort* hw = ((tt & 1) ? hbuf0 : hbuf1) + cb * HID + j0 + jl;
    if ((jl & 1) == 0) {
      unsigned pk = (unsigned)hv | (other << 16);
      asm volatile("global_store_dword %0, %1, off sc0 sc1" :: "v"(hw), "v"(pk) : "memory");
    }
    if (hT && tt == nsteps - 1) {
      hT[cb * HID + jglob] = hy;
      cT[cb * HID + jglob] = cy;
    }

    // defer bulk output stores to next iteration
    def_hy = hy;
    def_oidx = ((size_t)tt * BATCH + cb) * HID + jglob;
    def_df = 1.f - sumfg * 0.125f;
    def_di = sumin * 0.125f;

    // ---- flag barrier: own-line store + 64-lane gather poll ----
    if (tt < nsteps - 1) {
      asm volatile("s_waitcnt vmcnt(0)" ::: "memory");  // h store at LLC
      __syncthreads();
      if (w == 0) {
        unsigned tgt = (unsigned)(barbase + tt + 1);
        if (lane == 0) {
          unsigned* fp = barmem + (unsigned)blk * 16u;
          asm volatile("global_store_dword %0, %1, off sc0 sc1"
                       :: "v"(fp), "v"(tgt) : "memory");
        }
        const unsigned* mp = barmem + (unsigned)lane * 16u;
        while (true) {
          unsigned f;
          asm volatile("global_load_dword %0, %1, off sc0 sc1"
                       : "=v"(f) : "v"(mp) : "memory");
          asm volatile("s_waitcnt vmcnt(0)" ::: "memory");
          if (__all((int)(f >= tgt))) break;
        }
      }
      __syncthreads();
    }
  }
  // flush deferred stores of the last step
  out_hs[def_oidx] = def_hy;
  if (out_hs2) out_hs2[def_oidx] = def_hy;
  if (blk == 0 && jl == 0) {
    dfs[(nsteps - 1) * BATCH + cb] = def_df;
    dins[(nsteps - 1) * BATCH + cb] = def_di;
  }
  cws[cb * HID + jglob] = creg;
}

extern "C" void kernel_launch(void* const* d_in, const int* in_sizes, int n_in,
                              void* d_out, int out_size, void* d_ws, size_t ws_size,
                              hipStream_t stream) {
  const float* x   = (const float*)d_in[0];
  const float* h0  = (const float*)d_in[1];
  const float* c0  = (const float*)d_in[2];
  const float* Wih = (const float*)d_in[3];
  const float* bih = (const float*)d_in[4];
  const float* Whh = (const float*)d_in[5];
  const float* bhh = (const float*)d_in[6];
  float* out = (float*)d_out;

  const size_t OFF_OUTPUT = 0;                  // (512,64,1024)
  const size_t OFF_HT   = 33554432;             // (2,64,1024)
  const size_t OFF_CT   = OFF_HT + 131072;      // (2,64,8,128)
  const size_t OFF_OUTS = OFF_CT + 131072;      // (2,512,64,1024)
  const size_t OFF_DFS  = OFF_OUTS + 67108864;  // (2,512,64)
  const size_t OFF_DINS = OFF_DFS + 65536;      // (2,512,64)

  uint8_t* ws = (uint8_t*)d_ws;
  size_t off = 0;
  auto alloc = [&](size_t bytes) { size_t p = off; off = (off + bytes + 255) & ~(size_t)255; return p; };
  const size_t wT_sz = (size_t)GSZ * HID * 2;
  size_t o_WihT[2], o_WhhT[2];
  o_WihT[0] = alloc(wT_sz); o_WihT[1] = alloc(wT_sz);
  o_WhhT[0] = alloc(wT_sz); o_WhhT[1] = alloc(wT_sz);
  size_t o_h0b = alloc((size_t)BATCH * HID * 2);
  size_t o_h1b = alloc((size_t)BATCH * HID * 2);
  size_t o_c   = alloc((size_t)BATCH * HID * 4);
  size_t o_bar = alloc(4096);
  size_t fixed = off;
  const size_t unit = (size_t)BATCH * HID * 2 + (size_t)BATCH * GSZ * 2 + 512;
  int TC = 256;
  while (TC > 2 && fixed + (size_t)TC * unit > ws_size) TC >>= 1;
  size_t o_prevb = alloc((size_t)TC * BATCH * HID * 2);
  size_t o_tin   = alloc((size_t)TC * BATCH * GSZ * 2);

  ushort* hb0 = (ushort*)(ws + o_h0b);
  ushort* hb1 = (ushort*)(ws + o_h1b);
  float*  cst = (float*)(ws + o_c);
  unsigned* barmem = (unsigned*)(ws + o_bar);
  ushort* prevb = (ushort*)(ws + o_prevb);
  ushort* tin   = (ushort*)(ws + o_tin);

  dim3 tgrid((GSZ + 31) / 32, HID / 32);
  for (int l = 0; l < 2; ++l) {
    k_transpose_cast<<<tgrid, 256, 0, stream>>>(Wih + (size_t)l * HID * GSZ,
                                                (ushort*)(ws + o_WihT[l]), HID, GSZ);
    k_transpose_cast<<<tgrid, 256, 0, stream>>>(Whh + (size_t)l * HID * GSZ,
                                                (ushort*)(ws + o_WhhT[l]), HID, GSZ);
  }

  const int NB = (GSZ + 63) / 64;
  for (int l = 0; l < 2; ++l) {
    const float* prev = (l == 0) ? x : (out + OFF_OUTS);  // layer-0 hs in outs[0]
    const ushort* WihT = (const ushort*)(ws + o_WihT[l]);

    k_init_state<<<256, 256, 0, stream>>>(h0 + (size_t)l * BATCH * HID,
                                          c0 + (size_t)l * BATCH * HID,
                                          hb0, cst, barmem, BATCH * HID);

    int barbase = 0;  // cumulative barrier rounds this layer
    for (int t0 = 0; t0 < LSEQ; t0 += TC) {
      int nsteps = (LSEQ - t0 < TC) ? (LSEQ - t0) : TC;

      int count4 = nsteps * BATCH * HID / 4;
      int cblocks = (count4 + 255) / 256; if (cblocks > 2048) cblocks = 2048;
      k_cast4<<<cblocks, 256, 0, stream>>>(
          (const float4*)(prev + (size_t)t0 * BATCH * HID), prevb, count4);

      k_gemm_t<<<dim3(NB, nsteps), 256, 0, stream>>>(prevb, WihT,
                                                     bih + (size_t)l * GSZ, tin, HID, GSZ);

      bool last = (t0 + nsteps == LSEQ);
      const ushort* WhhT_p = (const ushort*)(ws + o_WhhT[l]);
      const float* bhh_p = bhh + (size_t)l * GSZ;
      const ushort* tin_p = tin;
      ushort* h0_p = hb0;
      ushort* h1_p = hb1;
      float* c_p = cst;
      float* ohs  = out + OFF_OUTS + ((size_t)l * LSEQ + t0) * BATCH * HID;
      float* ohs2 = (l == 1) ? (out + OFF_OUTPUT + (size_t)t0 * BATCH * HID) : nullptr;
      float* dfsp  = out + OFF_DFS  + ((size_t)l * LSEQ + t0) * BATCH;
      float* dinsp = out + OFF_DINS + ((size_t)l * LSEQ + t0) * BATCH;
      float* hTp = last ? (out + OFF_HT + (size_t)l * BATCH * HID) : nullptr;
      float* cTp = last ? (out + OFF_CT + (size_t)l * BATCH * HID) : nullptr;
      int nsteps_v = nsteps;
      int barbase_v = barbase;

      void* args[] = {&WhhT_p, &bhh_p, &tin_p, &h0_p, &h1_p, &c_p, &ohs, &ohs2,
                      &dfsp, &dinsp, &hTp, &cTp, &barmem, &nsteps_v, &barbase_v};
      hipLaunchCooperativeKernel((const void*)k_scan, dim3(NBLK), dim3(1024),
                                 args, 0, stream);
      barbase += nsteps - 1;

      // h parity: if nsteps is odd the final h landed in the "other" buffer
      if (nsteps & 1) { ushort* tmp = hb0; hb0 = hb1; hb1 = tmp; }
    }
  }
}

// Round 11
// 13866.655 us; speedup vs baseline: 2.6712x; 1.4677x over previous
//
#include <hip/hip_runtime.h>
#include <math.h>

#define LSEQ 512
#define BATCH 64
#define HID 1024
#define NCH 8
#define GSZ 4112
#define NB2 128   // 64 layer-0 blocks + 64 layer-1 blocks

typedef __bf16 bf16x8 __attribute__((ext_vector_type(8)));
typedef float f32x4 __attribute__((ext_vector_type(4)));
typedef unsigned u32x4 __attribute__((ext_vector_type(4)));

__device__ __forceinline__ ushort f2b(float f) {
  union { float f; unsigned u; } v; v.f = f;
  unsigned u = v.u;
  unsigned r = (u + 0x7FFFu + ((u >> 16) & 1u)) >> 16;  // RNE
  return (ushort)r;
}
__device__ __forceinline__ float b2f(ushort h) {
  union { unsigned u; float f; } v; v.u = (unsigned)h << 16; return v.f;
}
__device__ __forceinline__ float sigmoidf(float x) { return 1.f / (1.f + expf(-x)); }

// ---- transpose + cast: W (K x N) f32 -> WT (N x K) bf16 ----
__global__ __launch_bounds__(256) void k_transpose_cast(
    const float* __restrict__ W, ushort* __restrict__ WT, int K, int N) {
  __shared__ float tile[32][33];
  int n0 = blockIdx.x * 32, k0 = blockIdx.y * 32;
  int tx = threadIdx.x & 31, ty = threadIdx.x >> 5;
  #pragma unroll
  for (int i = ty; i < 32; i += 8) {
    int n = n0 + tx;
    tile[i][tx] = (n < N) ? W[(size_t)(k0 + i) * N + n] : 0.f;
  }
  __syncthreads();
  #pragma unroll
  for (int i = ty; i < 32; i += 8) {
    int n = n0 + i;
    if (n < N) WT[(size_t)n * K + k0 + tx] = f2b(tile[tx][i]);
  }
}

// ---- f32 -> bf16 cast (vectorized x4) ----
__global__ void k_cast4(const float4* __restrict__ in, ushort* __restrict__ out, int count4) {
  int stride = gridDim.x * blockDim.x;
  for (int i = blockIdx.x * blockDim.x + threadIdx.x; i < count4; i += stride) {
    float4 v = in[i];
    ushort4 o;
    o.x = f2b(v.x); o.y = f2b(v.y); o.z = f2b(v.z); o.w = f2b(v.w);
    *reinterpret_cast<ushort4*>(out + (size_t)i * 4) = o;
  }
}

// init: h0 layer0 -> h1ring[1], layer1 -> h2ring[1]; c both; flags zero
__global__ void k_init2(const float* __restrict__ h0, const float* __restrict__ c0,
                        ushort* __restrict__ h1b1, ushort* __restrict__ h2b1,
                        float* __restrict__ c1, float* __restrict__ c2,
                        unsigned* __restrict__ barmem) {
  int i = blockIdx.x * blockDim.x + threadIdx.x;
  const int n = BATCH * HID;
  if (i < n) { h1b1[i] = f2b(h0[i]); c1[i] = c0[i]; }
  else if (i < 2 * n) {
    int j = i - n;
    h2b1[j] = f2b(h0[n + j]); c2[j] = c0[n + j];
  }
  if (i < NB2 * 16) barmem[i] = 0u;
}

// Ct[t][col][batch] (bf16) = A[t*64+b][K](bf16) @ BT[col][K](bf16)^T + bias[col]
__global__ __launch_bounds__(256) void k_gemm_t(
    const ushort* __restrict__ A, const ushort* __restrict__ BT,
    const float* __restrict__ bias, ushort* __restrict__ Ct, int K, int N) {
  int col0 = blockIdx.x * 64;
  int t = blockIdx.y;
  int lane = threadIdx.x & 63;
  int w = threadIdx.x >> 6;
  int l15 = lane & 15;
  int koff = (lane >> 4) * 8;
  const ushort* Ap = A + (size_t)(t * 64 + w * 16 + l15) * K + koff;
  const ushort* Bp[4];
  int cols[4];
  #pragma unroll
  for (int cg = 0; cg < 4; ++cg) {
    int c_ = col0 + cg * 16 + l15;
    cols[cg] = c_;
    int cc = c_ < N ? c_ : N - 1;  // clamp reads on partial tile
    Bp[cg] = BT + (size_t)cc * K + koff;
  }
  f32x4 acc[4] = {};
  #pragma unroll 4
  for (int kk = 0; kk < K; kk += 32) {
    bf16x8 a = *reinterpret_cast<const bf16x8*>(Ap + kk);
    #pragma unroll
    for (int cg = 0; cg < 4; ++cg) {
      bf16x8 b = *reinterpret_cast<const bf16x8*>(Bp[cg] + kk);
      acc[cg] = __builtin_amdgcn_mfma_f32_16x16x32_bf16(a, b, acc[cg], 0, 0, 0);
    }
  }
  int crow = w * 16 + (lane >> 4) * 4;  // batch row base
  #pragma unroll
  for (int cg = 0; cg < 4; ++cg) {
    int c_ = cols[cg];
    if (c_ >= N) continue;
    float bv = bias[c_];
    ushort4 o;
    o.x = f2b(acc[cg][0] + bv); o.y = f2b(acc[cg][1] + bv);
    o.z = f2b(acc[cg][2] + bv); o.w = f2b(acc[cg][3] + bv);
    *reinterpret_cast<ushort4*>(&Ct[((size_t)t * GSZ + c_) * 64 + crow]) = o;
  }
}

// ---- fused 2-layer persistent scan: 128 blocks x 1024 threads ----
// Blocks 0..63: layer 0 (round-8 structure verbatim: 5 GEMM waves, one
// col-tile x 4 batch tiles, tin from HBM). Blocks 64..127: layer 1, lagging
// one round: gates = h0(t)@Wih1 + h1(t-1)@Whh1 (+both biases) as two K=1024
// LDS-staged GEMM passes into the same accumulators (no tin buffer at all).
// h rings (depth 2, parity = global t) exchanged via sc0/sc1 LLC ops; one
// global flag barrier (128 flags, load-polled) per round; rounds/chunk =
// nsteps+1 instead of 2*nsteps.
__global__ __launch_bounds__(1024, 4) void k_scan2(
    const ushort* __restrict__ WhhT0, const ushort* __restrict__ WhhT1,
    const ushort* __restrict__ WihT1,
    const float* __restrict__ bhh0, const float* __restrict__ bhh1,
    const float* __restrict__ bih1,
    const ushort* __restrict__ tin,   // [nsteps][GSZ][64] bf16 (layer-0 only)
    ushort* __restrict__ h1b0, ushort* __restrict__ h1b1,  // layer-0 h ring
    ushort* __restrict__ h2b0, ushort* __restrict__ h2b1,  // layer-1 h ring
    float* __restrict__ c1, float* __restrict__ c2,
    float* __restrict__ outs0, float* __restrict__ outs1,
    float* __restrict__ outdup,
    float* __restrict__ dfs0, float* __restrict__ dins0,
    float* __restrict__ dfs1, float* __restrict__ dins1,
    float* __restrict__ hT0, float* __restrict__ cT0,
    float* __restrict__ hT1, float* __restrict__ cT1,
    unsigned* __restrict__ barmem, int nsteps, int t0, int barbase) {
  __shared__ unsigned hlds[32768];              // 128 KB, XOR-swizzled h
  __shared__ __align__(16) float gbuf[80][68];  // [gate col][batch]

  const int tid = threadIdx.x;
  const int blk = blockIdx.x;
  const bool isL2 = blk >= 64;
  const int lblk = isL2 ? (blk - 64) : blk;
  const int j0 = lblk * 16;
  const int lane = tid & 63;
  const int w = tid >> 6;       // wave 0..15
  const int l15 = lane & 15;
  const int lg = lane >> 4;
  const int koff = lg * 8;

  // GEMM constants (round-8 scheme: 5 waves, one col-tile, 4 batch tiles)
  const int ct = (w < 5) ? w : 0;
  const int gcol = (ct == 0) ? l15 : (16 + (ct - 1) * 1024 + j0 + l15);
  const int grow = (ct == 0) ? l15 : (16 + (ct - 1) * 16 + l15);
  const ushort* bpA = (isL2 ? WhhT1 : WhhT0) + (size_t)gcol * HID + koff;
  const ushort* bpB = WihT1 + (size_t)gcol * HID + koff;  // layer-1 only
  const float bv = isL2 ? (bhh1[gcol] + bih1[gcol]) : bhh0[gcol];
  const int cr = lg * 4;
  const unsigned ab = (unsigned)l15 * 2048u + (unsigned)(lg * 16);
  const unsigned swz = (unsigned)(l15 & 7) << 4;

  // cell mapping
  const int cb = tid >> 4;
  const int jl = tid & 15;
  const int jglob = j0 + jl;
  const int rch = jglob >> 7;   // chunk index 0..7
  float creg = (isL2 ? c2 : c1)[cb * HID + jglob];

  float* out_my  = isL2 ? outs1 : outs0;
  float* dfs_my  = isL2 ? dfs1  : dfs0;
  float* dins_my = isL2 ? dins1 : dins0;

  float def_hy = 0.f, def_df = 0.f, def_di = 0.f;
  size_t def_oidx = 0;
  int def_didx = 0;
  bool have_def = false;

#define STAGE(hbase) do { \
    const u32x4* hs_ = (const u32x4*)(hbase); \
    u32x4 z0, z1, z2, z3, z4, z5, z6, z7; \
    asm volatile("global_load_dwordx4 %0, %1, off sc0 sc1" : "=v"(z0) : "v"(hs_ + tid)        : "memory"); \
    asm volatile("global_load_dwordx4 %0, %1, off sc0 sc1" : "=v"(z1) : "v"(hs_ + tid + 1024) : "memory"); \
    asm volatile("global_load_dwordx4 %0, %1, off sc0 sc1" : "=v"(z2) : "v"(hs_ + tid + 2048) : "memory"); \
    asm volatile("global_load_dwordx4 %0, %1, off sc0 sc1" : "=v"(z3) : "v"(hs_ + tid + 3072) : "memory"); \
    asm volatile("global_load_dwordx4 %0, %1, off sc0 sc1" : "=v"(z4) : "v"(hs_ + tid + 4096) : "memory"); \
    asm volatile("global_load_dwordx4 %0, %1, off sc0 sc1" : "=v"(z5) : "v"(hs_ + tid + 5120) : "memory"); \
    asm volatile("global_load_dwordx4 %0, %1, off sc0 sc1" : "=v"(z6) : "v"(hs_ + tid + 6144) : "memory"); \
    asm volatile("global_load_dwordx4 %0, %1, off sc0 sc1" : "=v"(z7) : "v"(hs_ + tid + 7168) : "memory"); \
    asm volatile("s_waitcnt vmcnt(0)" ::: "memory"); \
    __builtin_amdgcn_sched_barrier(0); \
    { unsigned b_; \
      b_ = (unsigned)tid * 16u;          *(u32x4*)((char*)hlds + (b_ ^ (((b_ >> 11) & 7u) << 4))) = z0; \
      b_ = (unsigned)(tid + 1024) * 16u; *(u32x4*)((char*)hlds + (b_ ^ (((b_ >> 11) & 7u) << 4))) = z1; \
      b_ = (unsigned)(tid + 2048) * 16u; *(u32x4*)((char*)hlds + (b_ ^ (((b_ >> 11) & 7u) << 4))) = z2; \
      b_ = (unsigned)(tid + 3072) * 16u; *(u32x4*)((char*)hlds + (b_ ^ (((b_ >> 11) & 7u) << 4))) = z3; \
      b_ = (unsigned)(tid + 4096) * 16u; *(u32x4*)((char*)hlds + (b_ ^ (((b_ >> 11) & 7u) << 4))) = z4; \
      b_ = (unsigned)(tid + 5120) * 16u; *(u32x4*)((char*)hlds + (b_ ^ (((b_ >> 11) & 7u) << 4))) = z5; \
      b_ = (unsigned)(tid + 6144) * 16u; *(u32x4*)((char*)hlds + (b_ ^ (((b_ >> 11) & 7u) << 4))) = z6; \
      b_ = (unsigned)(tid + 7168) * 16u; *(u32x4*)((char*)hlds + (b_ ^ (((b_ >> 11) & 7u) << 4))) = z7; \
    } \
    __syncthreads(); \
  } while (0)

#define GEMM_PASS(bp) do { \
    _Pragma("unroll 8") \
    for (int kb = 0; kb < 32; ++kb) { \
      bf16x8 b_ = *(const bf16x8*)((bp) + kb * 32); \
      unsigned o_ = ab + (unsigned)kb * 64u; \
      bf16x8 x0_ = *(const bf16x8*)((const char*)hlds + ((o_)           ^ swz)); \
      bf16x8 x1_ = *(const bf16x8*)((const char*)hlds + ((o_ + 32768u)  ^ swz)); \
      bf16x8 x2_ = *(const bf16x8*)((const char*)hlds + ((o_ + 65536u)  ^ swz)); \
      bf16x8 x3_ = *(const bf16x8*)((const char*)hlds + ((o_ + 98304u)  ^ swz)); \
      a0 = __builtin_amdgcn_mfma_f32_16x16x32_bf16(x0_, b_, a0, 0, 0, 0); \
      a1 = __builtin_amdgcn_mfma_f32_16x16x32_bf16(x1_, b_, a1, 0, 0, 0); \
      a2 = __builtin_amdgcn_mfma_f32_16x16x32_bf16(x2_, b_, a2, 0, 0, 0); \
      a3 = __builtin_amdgcn_mfma_f32_16x16x32_bf16(x3_, b_, a3, 0, 0, 0); \
    } \
  } while (0)

  for (int r = 0; r <= nsteps; ++r) {
    // flush deferred outputs from the previous round (overlaps staging)
    if (have_def) {
      out_my[def_oidx] = def_hy;
      if (isL2) outdup[def_oidx] = def_hy;
      if (lblk == 0 && jl == 0) {
        dfs_my[def_didx] = def_df;
        dins_my[def_didx] = def_di;
      }
      have_def = false;
    }

    const bool active = isL2 ? (r >= 1) : (r < nsteps);
    if (active) {
      const int t = isL2 ? (t0 + r - 1) : (t0 + r);
      const int tloc = isL2 ? (r - 1) : r;

      if (!isL2) {
        // layer 0: stage h0(t-1), one GEMM pass vs Whh0, tin epilogue
        STAGE(((t - 1) & 1) ? h1b1 : h1b0);
        if (w < 5) {
          const ushort* tp = tin + ((size_t)tloc * GSZ + gcol) * 64 + cr;
          ushort4 tv0 = *(const ushort4*)(tp);
          ushort4 tv1 = *(const ushort4*)(tp + 16);
          ushort4 tv2 = *(const ushort4*)(tp + 32);
          ushort4 tv3 = *(const ushort4*)(tp + 48);
          f32x4 a0 = {}, a1 = {}, a2 = {}, a3 = {};
          GEMM_PASS(bpA);
          f32x4 g;
          g[0] = a0[0] + bv + b2f(tv0.x); g[1] = a0[1] + bv + b2f(tv0.y);
          g[2] = a0[2] + bv + b2f(tv0.z); g[3] = a0[3] + bv + b2f(tv0.w);
          *(f32x4*)(&gbuf[grow][cr]) = g;
          g[0] = a1[0] + bv + b2f(tv1.x); g[1] = a1[1] + bv + b2f(tv1.y);
          g[2] = a1[2] + bv + b2f(tv1.z); g[3] = a1[3] + bv + b2f(tv1.w);
          *(f32x4*)(&gbuf[grow][16 + cr]) = g;
          g[0] = a2[0] + bv + b2f(tv2.x); g[1] = a2[1] + bv + b2f(tv2.y);
          g[2] = a2[2] + bv + b2f(tv2.z); g[3] = a2[3] + bv + b2f(tv2.w);
          *(f32x4*)(&gbuf[grow][32 + cr]) = g;
          g[0] = a3[0] + bv + b2f(tv3.x); g[1] = a3[1] + bv + b2f(tv3.y);
          g[2] = a3[2] + bv + b2f(tv3.z); g[3] = a3[3] + bv + b2f(tv3.w);
          *(f32x4*)(&gbuf[grow][48 + cr]) = g;
        }
        __syncthreads();
      } else {
        // layer 1: pass A = h1(t-1)@Whh1, restage, pass B = h0(t)@Wih1
        f32x4 a0 = {}, a1 = {}, a2 = {}, a3 = {};
        STAGE(((t - 1) & 1) ? h2b1 : h2b0);
        if (w < 5) GEMM_PASS(bpA);
        __syncthreads();                 // hlds reads done before restage
        STAGE((t & 1) ? h1b1 : h1b0);
        if (w < 5) {
          GEMM_PASS(bpB);
          f32x4 g;
          g[0] = a0[0] + bv; g[1] = a0[1] + bv; g[2] = a0[2] + bv; g[3] = a0[3] + bv;
          *(f32x4*)(&gbuf[grow][cr]) = g;
          g[0] = a1[0] + bv; g[1] = a1[1] + bv; g[2] = a1[2] + bv; g[3] = a1[3] + bv;
          *(f32x4*)(&gbuf[grow][16 + cr]) = g;
          g[0] = a2[0] + bv; g[1] = a2[1] + bv; g[2] = a2[2] + bv; g[3] = a2[3] + bv;
          *(f32x4*)(&gbuf[grow][32 + cr]) = g;
          g[0] = a3[0] + bv; g[1] = a3[1] + bv; g[2] = a3[2] + bv; g[3] = a3[3] + bv;
          *(f32x4*)(&gbuf[grow][48 + cr]) = g;
        }
        __syncthreads();
      }

      // ---- fused cell update ----
      float sm0[NCH], sm1[NCH];
      float m1 = -1e30f, m2 = -1e30f;
      #pragma unroll
      for (int i = 0; i < NCH; ++i) {
        sm0[i] = gbuf[i][cb];
        sm1[i] = gbuf[NCH + i][cb];
        m1 = fmaxf(m1, sm0[i]);
        m2 = fmaxf(m2, sm1[i]);
      }
      float s1 = 0.f, s2 = 0.f;
      #pragma unroll
      for (int i = 0; i < NCH; ++i) {
        sm0[i] = expf(sm0[i] - m1); s1 += sm0[i];
        sm1[i] = expf(sm1[i] - m2); s2 += sm1[i];
      }
      float r1 = 1.f / s1, r2 = 1.f / s2;
      float cum1 = 0.f, cum2 = 0.f, sumin = 0.f, sumfg = 0.f;
      float cing[NCH], cfg[NCH];
      #pragma unroll
      for (int i = 0; i < NCH; ++i) {
        cum1 += sm0[i] * r1; cing[i] = 1.f - cum1; sumin += cing[i];
        cum2 += sm1[i] * r2; cfg[i] = cum2; sumfg += cfg[i];
      }
      float go = gbuf[16 + jl][cb];
      float gc = gbuf[32 + jl][cb];
      float gi = gbuf[48 + jl][cb];
      float gf = gbuf[64 + jl][cb];
      float ov = cfg[rch] * cing[rch];
      float f_ = sigmoidf(gf) * ov + (cfg[rch] - ov);
      float i_ = sigmoidf(gi) * ov + (cing[rch] - ov);
      float cy = f_ * creg + i_ * tanhf(gc);
      float hy = sigmoidf(go) * tanhf(cy);
      creg = cy;

      // h store: write-through to LLC, packed bf16 pairs
      ushort hv = f2b(hy);
      unsigned other = (unsigned)__shfl_xor((int)(unsigned)hv, 1, 64);
      ushort* ring = isL2 ? ((t & 1) ? h2b1 : h2b0) : ((t & 1) ? h1b1 : h1b0);
      ushort* hw = ring + cb * HID + jglob;
      if ((jl & 1) == 0) {
        unsigned pk = (unsigned)hv | (other << 16);
        asm volatile("global_store_dword %0, %1, off sc0 sc1" :: "v"(hw), "v"(pk) : "memory");
      }
      if (!isL2 && hT0 && r == nsteps - 1) {
        hT0[cb * HID + jglob] = hy; cT0[cb * HID + jglob] = cy;
      }
      if (isL2 && hT1 && r == nsteps) {
        hT1[cb * HID + jglob] = hy; cT1[cb * HID + jglob] = cy;
      }

      def_hy = hy;
      def_oidx = ((size_t)tloc * BATCH + cb) * HID + jglob;
      def_didx = tloc * BATCH + cb;
      def_df = 1.f - sumfg * 0.125f;
      def_di = sumin * 0.125f;
      have_def = true;
    }

    // ---- global flag barrier over 128 blocks ----
    if (r < nsteps) {
      asm volatile("s_waitcnt vmcnt(0)" ::: "memory");  // h store at LLC
      __syncthreads();
      if (w == 0) {
        unsigned tgt = (unsigned)(barbase + r + 1);
        if (lane == 0) {
          unsigned* fp = barmem + (unsigned)blk * 16u;
          asm volatile("global_store_dword %0, %1, off sc0 sc1"
                       :: "v"(fp), "v"(tgt) : "memory");
        }
        const unsigned* mp0 = barmem + (unsigned)lane * 16u;
        const unsigned* mp1 = barmem + (unsigned)(64 + lane) * 16u;
        while (true) {
          unsigned f0, f1;
          asm volatile("global_load_dword %0, %1, off sc0 sc1"
                       : "=v"(f0) : "v"(mp0) : "memory");
          asm volatile("global_load_dword %0, %1, off sc0 sc1"
                       : "=v"(f1) : "v"(mp1) : "memory");
          asm volatile("s_waitcnt vmcnt(0)" ::: "memory");
          if (__all((int)(f0 >= tgt && f1 >= tgt))) break;
        }
      }
      __syncthreads();
    }
  }

  // final deferred flush (layer-1 role's last step)
  if (have_def) {
    out_my[def_oidx] = def_hy;
    if (isL2) outdup[def_oidx] = def_hy;
    if (lblk == 0 && jl == 0) {
      dfs_my[def_didx] = def_df;
      dins_my[def_didx] = def_di;
    }
  }
  (isL2 ? c2 : c1)[cb * HID + jglob] = creg;
#undef STAGE
#undef GEMM_PASS
}

extern "C" void kernel_launch(void* const* d_in, const int* in_sizes, int n_in,
                              void* d_out, int out_size, void* d_ws, size_t ws_size,
                              hipStream_t stream) {
  const float* x   = (const float*)d_in[0];
  const float* h0  = (const float*)d_in[1];
  const float* c0  = (const float*)d_in[2];
  const float* Wih = (const float*)d_in[3];
  const float* bih = (const float*)d_in[4];
  const float* Whh = (const float*)d_in[5];
  const float* bhh = (const float*)d_in[6];
  float* out = (float*)d_out;

  const size_t OFF_OUTPUT = 0;                  // (512,64,1024)
  const size_t OFF_HT   = 33554432;             // (2,64,1024)
  const size_t OFF_CT   = OFF_HT + 131072;      // (2,64,8,128)
  const size_t OFF_OUTS = OFF_CT + 131072;      // (2,512,64,1024)
  const size_t OFF_DFS  = OFF_OUTS + 67108864;  // (2,512,64)
  const size_t OFF_DINS = OFF_DFS + 65536;      // (2,512,64)

  uint8_t* ws = (uint8_t*)d_ws;
  size_t off = 0;
  auto alloc = [&](size_t bytes) { size_t p = off; off = (off + bytes + 255) & ~(size_t)255; return p; };
  const size_t wT_sz = (size_t)GSZ * HID * 2;
  size_t o_WihT[2], o_WhhT[2];
  o_WihT[0] = alloc(wT_sz); o_WihT[1] = alloc(wT_sz);
  o_WhhT[0] = alloc(wT_sz); o_WhhT[1] = alloc(wT_sz);
  size_t o_h1b0 = alloc((size_t)BATCH * HID * 2);
  size_t o_h1b1 = alloc((size_t)BATCH * HID * 2);
  size_t o_h2b0 = alloc((size_t)BATCH * HID * 2);
  size_t o_h2b1 = alloc((size_t)BATCH * HID * 2);
  size_t o_c1   = alloc((size_t)BATCH * HID * 4);
  size_t o_c2   = alloc((size_t)BATCH * HID * 4);
  size_t o_bar  = alloc(NB2 * 16 * 4);
  size_t fixed = off;
  const size_t unit = (size_t)BATCH * HID * 2 + (size_t)BATCH * GSZ * 2 + 512;
  int TC = 256;
  while (TC > 2 && fixed + (size_t)TC * unit > ws_size) TC >>= 1;
  size_t o_prevb = alloc((size_t)TC * BATCH * HID * 2);
  size_t o_tin   = alloc((size_t)TC * BATCH * GSZ * 2);

  ushort* h1b0 = (ushort*)(ws + o_h1b0);
  ushort* h1b1 = (ushort*)(ws + o_h1b1);
  ushort* h2b0 = (ushort*)(ws + o_h2b0);
  ushort* h2b1 = (ushort*)(ws + o_h2b1);
  float*  c1   = (float*)(ws + o_c1);
  float*  c2   = (float*)(ws + o_c2);
  unsigned* barmem = (unsigned*)(ws + o_bar);
  ushort* prevb = (ushort*)(ws + o_prevb);
  ushort* tin   = (ushort*)(ws + o_tin);

  // weight transposes (bf16, [GSZ][HID])
  dim3 tgrid((GSZ + 31) / 32, HID / 32);
  for (int l = 0; l < 2; ++l) {
    k_transpose_cast<<<tgrid, 256, 0, stream>>>(Wih + (size_t)l * HID * GSZ,
                                                (ushort*)(ws + o_WihT[l]), HID, GSZ);
    k_transpose_cast<<<tgrid, 256, 0, stream>>>(Whh + (size_t)l * HID * GSZ,
                                                (ushort*)(ws + o_WhhT[l]), HID, GSZ);
  }

  k_init2<<<(2 * BATCH * HID + 255) / 256, 256, 0, stream>>>(
      h0, c0, h1b1, h2b1, c1, c2, barmem);

  const int NB = (GSZ + 63) / 64;
  int barbase = 0;
  for (int t0 = 0; t0 < LSEQ; t0 += TC) {
    int nsteps = (LSEQ - t0 < TC) ? (LSEQ - t0) : TC;

    // layer-0 tin for this chunk (x only — independent of the scan)
    int count4 = nsteps * BATCH * HID / 4;
    int cblocks = (count4 + 255) / 256; if (cblocks > 2048) cblocks = 2048;
    k_cast4<<<cblocks, 256, 0, stream>>>(
        (const float4*)(x + (size_t)t0 * BATCH * HID), prevb, count4);
    k_gemm_t<<<dim3(NB, nsteps), 256, 0, stream>>>(prevb, (const ushort*)(ws + o_WihT[0]),
                                                   bih, tin, HID, GSZ);

    bool last = (t0 + nsteps == LSEQ);
    const ushort* WhhT0_p = (const ushort*)(ws + o_WhhT[0]);
    const ushort* WhhT1_p = (const ushort*)(ws + o_WhhT[1]);
    const ushort* WihT1_p = (const ushort*)(ws + o_WihT[1]);
    const float* bhh0_p = bhh;
    const float* bhh1_p = bhh + GSZ;
    const float* bih1_p = bih + GSZ;
    const ushort* tin_p = tin;
    float* outs0 = out + OFF_OUTS + (size_t)t0 * BATCH * HID;
    float* outs1 = out + OFF_OUTS + ((size_t)LSEQ + t0) * BATCH * HID;
    float* outdup = out + OFF_OUTPUT + (size_t)t0 * BATCH * HID;
    float* dfs0  = out + OFF_DFS  + (size_t)t0 * BATCH;
    float* dins0 = out + OFF_DINS + (size_t)t0 * BATCH;
    float* dfs1  = out + OFF_DFS  + ((size_t)LSEQ + t0) * BATCH;
    float* dins1 = out + OFF_DINS + ((size_t)LSEQ + t0) * BATCH;
    float* hT0 = last ? (out + OFF_HT) : nullptr;
    float* cT0 = last ? (out + OFF_CT) : nullptr;
    float* hT1 = last ? (out + OFF_HT + (size_t)BATCH * HID) : nullptr;
    float* cT1 = last ? (out + OFF_CT + (size_t)BATCH * HID) : nullptr;
    int nsteps_v = nsteps;
    int t0_v = t0;
    int barbase_v = barbase;

    void* args[] = {&WhhT0_p, &WhhT1_p, &WihT1_p, &bhh0_p, &bhh1_p, &bih1_p,
                    &tin_p, &h1b0, &h1b1, &h2b0, &h2b1, &c1, &c2,
                    &outs0, &outs1, &outdup, &dfs0, &dins0, &dfs1, &dins1,
                    &hT0, &cT0, &hT1, &cT1, &barmem, &nsteps_v, &t0_v, &barbase_v};
    hipLaunchCooperativeKernel((const void*)k_scan2, dim3(NB2), dim3(1024),
                               args, 0, stream);
    barbase += nsteps;
  }
}

// Round 12
// 12056.817 us; speedup vs baseline: 3.0722x; 1.1501x over previous
//
#include <hip/hip_runtime.h>
#include <math.h>

#define LSEQ 512
#define BATCH 64
#define HID 1024
#define NCH 8
#define GSZ 4112
#define NB2 128   // 64 layer-0 blocks + 64 layer-1 blocks

typedef __bf16 bf16x8 __attribute__((ext_vector_type(8)));
typedef float f32x4 __attribute__((ext_vector_type(4)));
typedef unsigned u32x4 __attribute__((ext_vector_type(4)));
typedef unsigned u32x2 __attribute__((ext_vector_type(2)));

__device__ __forceinline__ ushort f2b(float f) {
  union { float f; unsigned u; } v; v.f = f;
  unsigned u = v.u;
  unsigned r = (u + 0x7FFFu + ((u >> 16) & 1u)) >> 16;  // RNE
  return (ushort)r;
}
__device__ __forceinline__ float b2f(ushort h) {
  union { unsigned u; float f; } v; v.u = (unsigned)h << 16; return v.f;
}
__device__ __forceinline__ float sigmoidf(float x) { return 1.f / (1.f + expf(-x)); }

// ---- transpose + cast: W (K x N) f32 -> WT (N x K) bf16 ----
__global__ __launch_bounds__(256) void k_transpose_cast(
    const float* __restrict__ W, ushort* __restrict__ WT, int K, int N) {
  __shared__ float tile[32][33];
  int n0 = blockIdx.x * 32, k0 = blockIdx.y * 32;
  int tx = threadIdx.x & 31, ty = threadIdx.x >> 5;
  #pragma unroll
  for (int i = ty; i < 32; i += 8) {
    int n = n0 + tx;
    tile[i][tx] = (n < N) ? W[(size_t)(k0 + i) * N + n] : 0.f;
  }
  __syncthreads();
  #pragma unroll
  for (int i = ty; i < 32; i += 8) {
    int n = n0 + i;
    if (n < N) WT[(size_t)n * K + k0 + tx] = f2b(tile[tx][i]);
  }
}

// ---- f32 -> bf16 cast (vectorized x4) ----
__global__ void k_cast4(const float4* __restrict__ in, ushort* __restrict__ out, int count4) {
  int stride = gridDim.x * blockDim.x;
  for (int i = blockIdx.x * blockDim.x + threadIdx.x; i < count4; i += stride) {
    float4 v = in[i];
    ushort4 o;
    o.x = f2b(v.x); o.y = f2b(v.y); o.z = f2b(v.z); o.w = f2b(v.w);
    *reinterpret_cast<ushort4*>(out + (size_t)i * 4) = o;
  }
}

// init: h0 layer0 -> h1ring[1], layer1 -> h2ring[1]; c both; flags zero
__global__ void k_init2(const float* __restrict__ h0, const float* __restrict__ c0,
                        ushort* __restrict__ h1b1, ushort* __restrict__ h2b1,
                        float* __restrict__ c1, float* __restrict__ c2,
                        unsigned* __restrict__ barmem) {
  int i = blockIdx.x * blockDim.x + threadIdx.x;
  const int n = BATCH * HID;
  if (i < n) { h1b1[i] = f2b(h0[i]); c1[i] = c0[i]; }
  else if (i < 2 * n) {
    int j = i - n;
    h2b1[j] = f2b(h0[n + j]); c2[j] = c0[n + j];
  }
  if (i < NB2 * 16) barmem[i] = 0u;
}

// Ct[t][col][batch] (bf16) = A[t*64+b][K](bf16) @ BT[col][K](bf16)^T + bias[col]
__global__ __launch_bounds__(256) void k_gemm_t(
    const ushort* __restrict__ A, const ushort* __restrict__ BT,
    const float* __restrict__ bias, ushort* __restrict__ Ct, int K, int N) {
  int col0 = blockIdx.x * 64;
  int t = blockIdx.y;
  int lane = threadIdx.x & 63;
  int w = threadIdx.x >> 6;
  int l15 = lane & 15;
  int koff = (lane >> 4) * 8;
  const ushort* Ap = A + (size_t)(t * 64 + w * 16 + l15) * K + koff;
  const ushort* Bp[4];
  int cols[4];
  #pragma unroll
  for (int cg = 0; cg < 4; ++cg) {
    int c_ = col0 + cg * 16 + l15;
    cols[cg] = c_;
    int cc = c_ < N ? c_ : N - 1;  // clamp reads on partial tile
    Bp[cg] = BT + (size_t)cc * K + koff;
  }
  f32x4 acc[4] = {};
  #pragma unroll 4
  for (int kk = 0; kk < K; kk += 32) {
    bf16x8 a = *reinterpret_cast<const bf16x8*>(Ap + kk);
    #pragma unroll
    for (int cg = 0; cg < 4; ++cg) {
      bf16x8 b = *reinterpret_cast<const bf16x8*>(Bp[cg] + kk);
      acc[cg] = __builtin_amdgcn_mfma_f32_16x16x32_bf16(a, b, acc[cg], 0, 0, 0);
    }
  }
  int crow = w * 16 + (lane >> 4) * 4;  // batch row base
  #pragma unroll
  for (int cg = 0; cg < 4; ++cg) {
    int c_ = cols[cg];
    if (c_ >= N) continue;
    float bv = bias[c_];
    ushort4 o;
    o.x = f2b(acc[cg][0] + bv); o.y = f2b(acc[cg][1] + bv);
    o.z = f2b(acc[cg][2] + bv); o.w = f2b(acc[cg][3] + bv);
    *reinterpret_cast<ushort4*>(&Ct[((size_t)t * GSZ + c_) * 64 + crow]) = o;
  }
}

// ---- fused 2-layer persistent scan: 128 blocks x 1024 threads ----
// Round-11 structure + two targeted fixes:
//  (1) nt (non-temporal) hints on streaming data (tin loads, output stores)
//      so weight B-fragments stay L2-resident across rounds;
//  (2) layer-1 issues its pass-B h-ring loads BEFORE pass-A's GEMM (data is
//      final since the round-start barrier) -> second STAGE latency hidden.
__global__ __launch_bounds__(1024, 2) void k_scan2(
    const ushort* __restrict__ WhhT0, const ushort* __restrict__ WhhT1,
    const ushort* __restrict__ WihT1,
    const float* __restrict__ bhh0, const float* __restrict__ bhh1,
    const float* __restrict__ bih1,
    const ushort* __restrict__ tin,   // [nsteps][GSZ][64] bf16 (layer-0 only)
    ushort* __restrict__ h1b0, ushort* __restrict__ h1b1,  // layer-0 h ring
    ushort* __restrict__ h2b0, ushort* __restrict__ h2b1,  // layer-1 h ring
    float* __restrict__ c1, float* __restrict__ c2,
    float* __restrict__ outs0, float* __restrict__ outs1,
    float* __restrict__ outdup,
    float* __restrict__ dfs0, float* __restrict__ dins0,
    float* __restrict__ dfs1, float* __restrict__ dins1,
    float* __restrict__ hT0, float* __restrict__ cT0,
    float* __restrict__ hT1, float* __restrict__ cT1,
    unsigned* __restrict__ barmem, int nsteps, int t0, int barbase) {
  __shared__ unsigned hlds[32768];              // 128 KB, XOR-swizzled h
  __shared__ __align__(16) float gbuf[80][68];  // [gate col][batch]

  const int tid = threadIdx.x;
  const int blk = blockIdx.x;
  const bool isL2 = blk >= 64;
  const int lblk = isL2 ? (blk - 64) : blk;
  const int j0 = lblk * 16;
  const int lane = tid & 63;
  const int w = tid >> 6;       // wave 0..15
  const int l15 = lane & 15;
  const int lg = lane >> 4;
  const int koff = lg * 8;

  // GEMM constants (5 waves, one col-tile, 4 batch tiles each)
  const int ct = (w < 5) ? w : 0;
  const int gcol = (ct == 0) ? l15 : (16 + (ct - 1) * 1024 + j0 + l15);
  const int grow = (ct == 0) ? l15 : (16 + (ct - 1) * 16 + l15);
  const ushort* bpA = (isL2 ? WhhT1 : WhhT0) + (size_t)gcol * HID + koff;
  const ushort* bpB = WihT1 + (size_t)gcol * HID + koff;  // layer-1 only
  const float bv = isL2 ? (bhh1[gcol] + bih1[gcol]) : bhh0[gcol];
  const int cr = lg * 4;
  const unsigned ab = (unsigned)l15 * 2048u + (unsigned)(lg * 16);
  const unsigned swz = (unsigned)(l15 & 7) << 4;

  // cell mapping
  const int cb = tid >> 4;
  const int jl = tid & 15;
  const int jglob = j0 + jl;
  const int rch = jglob >> 7;   // chunk index 0..7
  float creg = (isL2 ? c2 : c1)[cb * HID + jglob];

  float* out_my  = isL2 ? outs1 : outs0;
  float* dfs_my  = isL2 ? dfs1  : dfs0;
  float* dins_my = isL2 ? dins1 : dins0;

  float def_hy = 0.f, def_df = 0.f, def_di = 0.f;
  size_t def_oidx = 0;
  int def_didx = 0;
  bool have_def = false;

#define LOAD8(hbase) do { \
    const u32x4* hs_ = (const u32x4*)(hbase); \
    asm volatile("global_load_dwordx4 %0, %1, off sc0 sc1" : "=v"(z0) : "v"(hs_ + tid)        : "memory"); \
    asm volatile("global_load_dwordx4 %0, %1, off sc0 sc1" : "=v"(z1) : "v"(hs_ + tid + 1024) : "memory"); \
    asm volatile("global_load_dwordx4 %0, %1, off sc0 sc1" : "=v"(z2) : "v"(hs_ + tid + 2048) : "memory"); \
    asm volatile("global_load_dwordx4 %0, %1, off sc0 sc1" : "=v"(z3) : "v"(hs_ + tid + 3072) : "memory"); \
    asm volatile("global_load_dwordx4 %0, %1, off sc0 sc1" : "=v"(z4) : "v"(hs_ + tid + 4096) : "memory"); \
    asm volatile("global_load_dwordx4 %0, %1, off sc0 sc1" : "=v"(z5) : "v"(hs_ + tid + 5120) : "memory"); \
    asm volatile("global_load_dwordx4 %0, %1, off sc0 sc1" : "=v"(z6) : "v"(hs_ + tid + 6144) : "memory"); \
    asm volatile("global_load_dwordx4 %0, %1, off sc0 sc1" : "=v"(z7) : "v"(hs_ + tid + 7168) : "memory"); \
  } while (0)

#define WRITE8() do { \
    unsigned b_; \
    b_ = (unsigned)tid * 16u;          *(u32x4*)((char*)hlds + (b_ ^ (((b_ >> 11) & 7u) << 4))) = z0; \
    b_ = (unsigned)(tid + 1024) * 16u; *(u32x4*)((char*)hlds + (b_ ^ (((b_ >> 11) & 7u) << 4))) = z1; \
    b_ = (unsigned)(tid + 2048) * 16u; *(u32x4*)((char*)hlds + (b_ ^ (((b_ >> 11) & 7u) << 4))) = z2; \
    b_ = (unsigned)(tid + 3072) * 16u; *(u32x4*)((char*)hlds + (b_ ^ (((b_ >> 11) & 7u) << 4))) = z3; \
    b_ = (unsigned)(tid + 4096) * 16u; *(u32x4*)((char*)hlds + (b_ ^ (((b_ >> 11) & 7u) << 4))) = z4; \
    b_ = (unsigned)(tid + 5120) * 16u; *(u32x4*)((char*)hlds + (b_ ^ (((b_ >> 11) & 7u) << 4))) = z5; \
    b_ = (unsigned)(tid + 6144) * 16u; *(u32x4*)((char*)hlds + (b_ ^ (((b_ >> 11) & 7u) << 4))) = z6; \
    b_ = (unsigned)(tid + 7168) * 16u; *(u32x4*)((char*)hlds + (b_ ^ (((b_ >> 11) & 7u) << 4))) = z7; \
  } while (0)

#define GEMM_PASS(bp) do { \
    _Pragma("unroll 8") \
    for (int kb = 0; kb < 32; ++kb) { \
      bf16x8 b_ = *(const bf16x8*)((bp) + kb * 32); \
      unsigned o_ = ab + (unsigned)kb * 64u; \
      bf16x8 x0_ = *(const bf16x8*)((const char*)hlds + ((o_)           ^ swz)); \
      bf16x8 x1_ = *(const bf16x8*)((const char*)hlds + ((o_ + 32768u)  ^ swz)); \
      bf16x8 x2_ = *(const bf16x8*)((const char*)hlds + ((o_ + 65536u)  ^ swz)); \
      bf16x8 x3_ = *(const bf16x8*)((const char*)hlds + ((o_ + 98304u)  ^ swz)); \
      a0 = __builtin_amdgcn_mfma_f32_16x16x32_bf16(x0_, b_, a0, 0, 0, 0); \
      a1 = __builtin_amdgcn_mfma_f32_16x16x32_bf16(x1_, b_, a1, 0, 0, 0); \
      a2 = __builtin_amdgcn_mfma_f32_16x16x32_bf16(x2_, b_, a2, 0, 0, 0); \
      a3 = __builtin_amdgcn_mfma_f32_16x16x32_bf16(x3_, b_, a3, 0, 0, 0); \
    } \
  } while (0)

  for (int r = 0; r <= nsteps; ++r) {
    // flush deferred outputs from the previous round (nt: don't pollute L2)
    if (have_def) {
      asm volatile("global_store_dword %0, %1, off nt"
                   :: "v"(&out_my[def_oidx]), "v"(def_hy) : "memory");
      if (isL2)
        asm volatile("global_store_dword %0, %1, off nt"
                     :: "v"(&outdup[def_oidx]), "v"(def_hy) : "memory");
      if (lblk == 0 && jl == 0) {
        dfs_my[def_didx] = def_df;
        dins_my[def_didx] = def_di;
      }
      have_def = false;
    }

    const bool active = isL2 ? (r >= 1) : (r < nsteps);
    if (active) {
      const int t = isL2 ? (t0 + r - 1) : (t0 + r);
      const int tloc = isL2 ? (r - 1) : r;

      if (!isL2) {
        // layer 0: stage h0(t-1), GEMM vs Whh0, tin (nt) epilogue
        u32x4 z0, z1, z2, z3, z4, z5, z6, z7;
        LOAD8(((t - 1) & 1) ? h1b1 : h1b0);
        asm volatile("s_waitcnt vmcnt(0)" ::: "memory");
        __builtin_amdgcn_sched_barrier(0);
        WRITE8();
        __syncthreads();
        if (w < 5) {
          const ushort* tp = tin + ((size_t)tloc * GSZ + gcol) * 64 + cr;
          u32x2 q0, q1, q2, q3;
          asm volatile("global_load_dwordx2 %0, %1, off nt" : "=v"(q0) : "v"(tp)      : "memory");
          asm volatile("global_load_dwordx2 %0, %1, off nt" : "=v"(q1) : "v"(tp + 16) : "memory");
          asm volatile("global_load_dwordx2 %0, %1, off nt" : "=v"(q2) : "v"(tp + 32) : "memory");
          asm volatile("global_load_dwordx2 %0, %1, off nt" : "=v"(q3) : "v"(tp + 48) : "memory");
          f32x4 a0 = {}, a1 = {}, a2 = {}, a3 = {};
          GEMM_PASS(bpA);
          asm volatile("s_waitcnt vmcnt(0)" ::: "memory");
          __builtin_amdgcn_sched_barrier(0);
          ushort4 tv0, tv1, tv2, tv3;
          *(u32x2*)&tv0 = q0; *(u32x2*)&tv1 = q1;
          *(u32x2*)&tv2 = q2; *(u32x2*)&tv3 = q3;
          f32x4 g;
          g[0] = a0[0] + bv + b2f(tv0.x); g[1] = a0[1] + bv + b2f(tv0.y);
          g[2] = a0[2] + bv + b2f(tv0.z); g[3] = a0[3] + bv + b2f(tv0.w);
          *(f32x4*)(&gbuf[grow][cr]) = g;
          g[0] = a1[0] + bv + b2f(tv1.x); g[1] = a1[1] + bv + b2f(tv1.y);
          g[2] = a1[2] + bv + b2f(tv1.z); g[3] = a1[3] + bv + b2f(tv1.w);
          *(f32x4*)(&gbuf[grow][16 + cr]) = g;
          g[0] = a2[0] + bv + b2f(tv2.x); g[1] = a2[1] + bv + b2f(tv2.y);
          g[2] = a2[2] + bv + b2f(tv2.z); g[3] = a2[3] + bv + b2f(tv2.w);
          *(f32x4*)(&gbuf[grow][32 + cr]) = g;
          g[0] = a3[0] + bv + b2f(tv3.x); g[1] = a3[1] + bv + b2f(tv3.y);
          g[2] = a3[2] + bv + b2f(tv3.z); g[3] = a3[3] + bv + b2f(tv3.w);
          *(f32x4*)(&gbuf[grow][48 + cr]) = g;
        }
        __syncthreads();
      } else {
        // layer 1: pass A = h1(t-1)@Whh1 with pass-B loads in flight, then
        // pass B = h0(t)@Wih1. Both h's final since the round-start barrier.
        f32x4 a0 = {}, a1 = {}, a2 = {}, a3 = {};
        {
          u32x4 z0, z1, z2, z3, z4, z5, z6, z7;
          LOAD8(((t - 1) & 1) ? h2b1 : h2b0);
          asm volatile("s_waitcnt vmcnt(0)" ::: "memory");
          __builtin_amdgcn_sched_barrier(0);
          WRITE8();
          __syncthreads();
        }
        {
          u32x4 z0, z1, z2, z3, z4, z5, z6, z7;
          LOAD8((t & 1) ? h1b1 : h1b0);   // fire early; completes under pass A
          if (w < 5) GEMM_PASS(bpA);
          asm volatile("s_waitcnt vmcnt(0)" ::: "memory");
          __builtin_amdgcn_sched_barrier(0);
          __syncthreads();                 // pass-A hlds reads complete
          WRITE8();
          __syncthreads();
        }
        if (w < 5) {
          GEMM_PASS(bpB);
          f32x4 g;
          g[0] = a0[0] + bv; g[1] = a0[1] + bv; g[2] = a0[2] + bv; g[3] = a0[3] + bv;
          *(f32x4*)(&gbuf[grow][cr]) = g;
          g[0] = a1[0] + bv; g[1] = a1[1] + bv; g[2] = a1[2] + bv; g[3] = a1[3] + bv;
          *(f32x4*)(&gbuf[grow][16 + cr]) = g;
          g[0] = a2[0] + bv; g[1] = a2[1] + bv; g[2] = a2[2] + bv; g[3] = a2[3] + bv;
          *(f32x4*)(&gbuf[grow][32 + cr]) = g;
          g[0] = a3[0] + bv; g[1] = a3[1] + bv; g[2] = a3[2] + bv; g[3] = a3[3] + bv;
          *(f32x4*)(&gbuf[grow][48 + cr]) = g;
        }
        __syncthreads();
      }

      // ---- fused cell update ----
      float sm0[NCH], sm1[NCH];
      float m1 = -1e30f, m2 = -1e30f;
      #pragma unroll
      for (int i = 0; i < NCH; ++i) {
        sm0[i] = gbuf[i][cb];
        sm1[i] = gbuf[NCH + i][cb];
        m1 = fmaxf(m1, sm0[i]);
        m2 = fmaxf(m2, sm1[i]);
      }
      float s1 = 0.f, s2 = 0.f;
      #pragma unroll
      for (int i = 0; i < NCH; ++i) {
        sm0[i] = expf(sm0[i] - m1); s1 += sm0[i];
        sm1[i] = expf(sm1[i] - m2); s2 += sm1[i];
      }
      float r1 = 1.f / s1, r2 = 1.f / s2;
      float cum1 = 0.f, cum2 = 0.f, sumin = 0.f, sumfg = 0.f;
      float cing[NCH], cfg[NCH];
      #pragma unroll
      for (int i = 0; i < NCH; ++i) {
        cum1 += sm0[i] * r1; cing[i] = 1.f - cum1; sumin += cing[i];
        cum2 += sm1[i] * r2; cfg[i] = cum2; sumfg += cfg[i];
      }
      float go = gbuf[16 + jl][cb];
      float gc = gbuf[32 + jl][cb];
      float gi = gbuf[48 + jl][cb];
      float gf = gbuf[64 + jl][cb];
      float ov = cfg[rch] * cing[rch];
      float f_ = sigmoidf(gf) * ov + (cfg[rch] - ov);
      float i_ = sigmoidf(gi) * ov + (cing[rch] - ov);
      float cy = f_ * creg + i_ * tanhf(gc);
      float hy = sigmoidf(go) * tanhf(cy);
      creg = cy;

      // h store: write-through to LLC, packed bf16 pairs
      ushort hv = f2b(hy);
      unsigned other = (unsigned)__shfl_xor((int)(unsigned)hv, 1, 64);
      ushort* ring = isL2 ? ((t & 1) ? h2b1 : h2b0) : ((t & 1) ? h1b1 : h1b0);
      ushort* hw = ring + cb * HID + jglob;
      if ((jl & 1) == 0) {
        unsigned pk = (unsigned)hv | (other << 16);
        asm volatile("global_store_dword %0, %1, off sc0 sc1" :: "v"(hw), "v"(pk) : "memory");
      }
      if (!isL2 && hT0 && r == nsteps - 1) {
        hT0[cb * HID + jglob] = hy; cT0[cb * HID + jglob] = cy;
      }
      if (isL2 && hT1 && r == nsteps) {
        hT1[cb * HID + jglob] = hy; cT1[cb * HID + jglob] = cy;
      }

      def_hy = hy;
      def_oidx = ((size_t)tloc * BATCH + cb) * HID + jglob;
      def_didx = tloc * BATCH + cb;
      def_df = 1.f - sumfg * 0.125f;
      def_di = sumin * 0.125f;
      have_def = true;
    }

    // ---- global flag barrier over 128 blocks ----
    if (r < nsteps) {
      asm volatile("s_waitcnt vmcnt(0)" ::: "memory");  // h store at LLC
      __syncthreads();
      if (w == 0) {
        unsigned tgt = (unsigned)(barbase + r + 1);
        if (lane == 0) {
          unsigned* fp = barmem + (unsigned)blk * 16u;
          asm volatile("global_store_dword %0, %1, off sc0 sc1"
                       :: "v"(fp), "v"(tgt) : "memory");
        }
        const unsigned* mp0 = barmem + (unsigned)lane * 16u;
        const unsigned* mp1 = barmem + (unsigned)(64 + lane) * 16u;
        while (true) {
          unsigned f0, f1;
          asm volatile("global_load_dword %0, %1, off sc0 sc1"
                       : "=v"(f0) : "v"(mp0) : "memory");
          asm volatile("global_load_dword %0, %1, off sc0 sc1"
                       : "=v"(f1) : "v"(mp1) : "memory");
          asm volatile("s_waitcnt vmcnt(0)" ::: "memory");
          if (__all((int)(f0 >= tgt && f1 >= tgt))) break;
        }
      }
      __syncthreads();
    }
  }

  // final deferred flush (layer-1 role's last step)
  if (have_def) {
    out_my[def_oidx] = def_hy;
    if (isL2) outdup[def_oidx] = def_hy;
    if (lblk == 0 && jl == 0) {
      dfs_my[def_didx] = def_df;
      dins_my[def_didx] = def_di;
    }
  }
  (isL2 ? c2 : c1)[cb * HID + jglob] = creg;
#undef LOAD8
#undef WRITE8
#undef GEMM_PASS
}

extern "C" void kernel_launch(void* const* d_in, const int* in_sizes, int n_in,
                              void* d_out, int out_size, void* d_ws, size_t ws_size,
                              hipStream_t stream) {
  const float* x   = (const float*)d_in[0];
  const float* h0  = (const float*)d_in[1];
  const float* c0  = (const float*)d_in[2];
  const float* Wih = (const float*)d_in[3];
  const float* bih = (const float*)d_in[4];
  const float* Whh = (const float*)d_in[5];
  const float* bhh = (const float*)d_in[6];
  float* out = (float*)d_out;

  const size_t OFF_OUTPUT = 0;                  // (512,64,1024)
  const size_t OFF_HT   = 33554432;             // (2,64,1024)
  const size_t OFF_CT   = OFF_HT + 131072;      // (2,64,8,128)
  const size_t OFF_OUTS = OFF_CT + 131072;      // (2,512,64,1024)
  const size_t OFF_DFS  = OFF_OUTS + 67108864;  // (2,512,64)
  const size_t OFF_DINS = OFF_DFS + 65536;      // (2,512,64)

  uint8_t* ws = (uint8_t*)d_ws;
  size_t off = 0;
  auto alloc = [&](size_t bytes) { size_t p = off; off = (off + bytes + 255) & ~(size_t)255; return p; };
  const size_t wT_sz = (size_t)GSZ * HID * 2;
  size_t o_WihT[2], o_WhhT[2];
  o_WihT[0] = alloc(wT_sz); o_WihT[1] = alloc(wT_sz);
  o_WhhT[0] = alloc(wT_sz); o_WhhT[1] = alloc(wT_sz);
  size_t o_h1b0 = alloc((size_t)BATCH * HID * 2);
  size_t o_h1b1 = alloc((size_t)BATCH * HID * 2);
  size_t o_h2b0 = alloc((size_t)BATCH * HID * 2);
  size_t o_h2b1 = alloc((size_t)BATCH * HID * 2);
  size_t o_c1   = alloc((size_t)BATCH * HID * 4);
  size_t o_c2   = alloc((size_t)BATCH * HID * 4);
  size_t o_bar  = alloc(NB2 * 16 * 4);
  size_t fixed = off;
  const size_t unit = (size_t)BATCH * HID * 2 + (size_t)BATCH * GSZ * 2 + 512;
  int TC = 256;
  while (TC > 2 && fixed + (size_t)TC * unit > ws_size) TC >>= 1;
  size_t o_prevb = alloc((size_t)TC * BATCH * HID * 2);
  size_t o_tin   = alloc((size_t)TC * BATCH * GSZ * 2);

  ushort* h1b0 = (ushort*)(ws + o_h1b0);
  ushort* h1b1 = (ushort*)(ws + o_h1b1);
  ushort* h2b0 = (ushort*)(ws + o_h2b0);
  ushort* h2b1 = (ushort*)(ws + o_h2b1);
  float*  c1   = (float*)(ws + o_c1);
  float*  c2   = (float*)(ws + o_c2);
  unsigned* barmem = (unsigned*)(ws + o_bar);
  ushort* prevb = (ushort*)(ws + o_prevb);
  ushort* tin   = (ushort*)(ws + o_tin);

  // weight transposes (bf16, [GSZ][HID])
  dim3 tgrid((GSZ + 31) / 32, HID / 32);
  for (int l = 0; l < 2; ++l) {
    k_transpose_cast<<<tgrid, 256, 0, stream>>>(Wih + (size_t)l * HID * GSZ,
                                                (ushort*)(ws + o_WihT[l]), HID, GSZ);
    k_transpose_cast<<<tgrid, 256, 0, stream>>>(Whh + (size_t)l * HID * GSZ,
                                                (ushort*)(ws + o_WhhT[l]), HID, GSZ);
  }

  k_init2<<<(2 * BATCH * HID + 255) / 256, 256, 0, stream>>>(
      h0, c0, h1b1, h2b1, c1, c2, barmem);

  const int NB = (GSZ + 63) / 64;
  int barbase = 0;
  for (int t0 = 0; t0 < LSEQ; t0 += TC) {
    int nsteps = (LSEQ - t0 < TC) ? (LSEQ - t0) : TC;

    // layer-0 tin for this chunk (x only — independent of the scan)
    int count4 = nsteps * BATCH * HID / 4;
    int cblocks = (count4 + 255) / 256; if (cblocks > 2048) cblocks = 2048;
    k_cast4<<<cblocks, 256, 0, stream>>>(
        (const float4*)(x + (size_t)t0 * BATCH * HID), prevb, count4);
    k_gemm_t<<<dim3(NB, nsteps), 256, 0, stream>>>(prevb, (const ushort*)(ws + o_WihT[0]),
                                                   bih, tin, HID, GSZ);

    bool last = (t0 + nsteps == LSEQ);
    const ushort* WhhT0_p = (const ushort*)(ws + o_WhhT[0]);
    const ushort* WhhT1_p = (const ushort*)(ws + o_WhhT[1]);
    const ushort* WihT1_p = (const ushort*)(ws + o_WihT[1]);
    const float* bhh0_p = bhh;
    const float* bhh1_p = bhh + GSZ;
    const float* bih1_p = bih + GSZ;
    const ushort* tin_p = tin;
    float* outs0 = out + OFF_OUTS + (size_t)t0 * BATCH * HID;
    float* outs1 = out + OFF_OUTS + ((size_t)LSEQ + t0) * BATCH * HID;
    float* outdup = out + OFF_OUTPUT + (size_t)t0 * BATCH * HID;
    float* dfs0  = out + OFF_DFS  + (size_t)t0 * BATCH;
    float* dins0 = out + OFF_DINS + (size_t)t0 * BATCH;
    float* dfs1  = out + OFF_DFS  + ((size_t)LSEQ + t0) * BATCH;
    float* dins1 = out + OFF_DINS + ((size_t)LSEQ + t0) * BATCH;
    float* hT0 = last ? (out + OFF_HT) : nullptr;
    float* cT0 = last ? (out + OFF_CT) : nullptr;
    float* hT1 = last ? (out + OFF_HT + (size_t)BATCH * HID) : nullptr;
    float* cT1 = last ? (out + OFF_CT + (size_t)BATCH * HID) : nullptr;
    int nsteps_v = nsteps;
    int t0_v = t0;
    int barbase_v = barbase;

    void* args[] = {&WhhT0_p, &WhhT1_p, &WihT1_p, &bhh0_p, &bhh1_p, &bih1_p,
                    &tin_p, &h1b0, &h1b1, &h2b0, &h2b1, &c1, &c2,
                    &outs0, &outs1, &outdup, &dfs0, &dins0, &dfs1, &dins1,
                    &hT0, &cT0, &hT1, &cT1, &barmem, &nsteps_v, &t0_v, &barbase_v};
    hipLaunchCooperativeKernel((const void*)k_scan2, dim3(NB2), dim3(1024),
                               args, 0, stream);
    barbase += nsteps;
  }
}

// Round 13
// 11516.559 us; speedup vs baseline: 3.2163x; 1.0469x over previous
//
#include <hip/hip_runtime.h>
#include <math.h>

#define LSEQ 512
#define BATCH 64
#define HID 1024
#define NCH 8
#define GSZ 4112
#define NB2 128   // 64 layer-0 blocks + 64 layer-1 blocks

typedef __bf16 bf16x8 __attribute__((ext_vector_type(8)));
typedef float f32x4 __attribute__((ext_vector_type(4)));
typedef float f32x16 __attribute__((ext_vector_type(16)));
typedef unsigned u32x4 __attribute__((ext_vector_type(4)));
typedef unsigned u32x2 __attribute__((ext_vector_type(2)));

__device__ __forceinline__ ushort f2b(float f) {
  union { float f; unsigned u; } v; v.f = f;
  unsigned u = v.u;
  unsigned r = (u + 0x7FFFu + ((u >> 16) & 1u)) >> 16;  // RNE
  return (ushort)r;
}
__device__ __forceinline__ float b2f(ushort h) {
  union { unsigned u; float f; } v; v.u = (unsigned)h << 16; return v.f;
}
__device__ __forceinline__ float sigmoidf(float x) { return 1.f / (1.f + expf(-x)); }

// ---- transpose + cast: W (K x N) f32 -> WT (N x K) bf16 ----
__global__ __launch_bounds__(256) void k_transpose_cast(
    const float* __restrict__ W, ushort* __restrict__ WT, int K, int N) {
  __shared__ float tile[32][33];
  int n0 = blockIdx.x * 32, k0 = blockIdx.y * 32;
  int tx = threadIdx.x & 31, ty = threadIdx.x >> 5;
  #pragma unroll
  for (int i = ty; i < 32; i += 8) {
    int n = n0 + tx;
    tile[i][tx] = (n < N) ? W[(size_t)(k0 + i) * N + n] : 0.f;
  }
  __syncthreads();
  #pragma unroll
  for (int i = ty; i < 32; i += 8) {
    int n = n0 + i;
    if (n < N) WT[(size_t)n * K + k0 + tx] = f2b(tile[tx][i]);
  }
}

// ---- f32 -> bf16 cast (vectorized x4) ----
__global__ void k_cast4(const float4* __restrict__ in, ushort* __restrict__ out, int count4) {
  int stride = gridDim.x * blockDim.x;
  for (int i = blockIdx.x * blockDim.x + threadIdx.x; i < count4; i += stride) {
    float4 v = in[i];
    ushort4 o;
    o.x = f2b(v.x); o.y = f2b(v.y); o.z = f2b(v.z); o.w = f2b(v.w);
    *reinterpret_cast<ushort4*>(out + (size_t)i * 4) = o;
  }
}

// init: h0 layer0 -> h1ring[1], layer1 -> h2ring[1]; c both; flags zero
__global__ void k_init2(const float* __restrict__ h0, const float* __restrict__ c0,
                        ushort* __restrict__ h1b1, ushort* __restrict__ h2b1,
                        float* __restrict__ c1, float* __restrict__ c2,
                        unsigned* __restrict__ barmem) {
  int i = blockIdx.x * blockDim.x + threadIdx.x;
  const int n = BATCH * HID;
  if (i < n) { h1b1[i] = f2b(h0[i]); c1[i] = c0[i]; }
  else if (i < 2 * n) {
    int j = i - n;
    h2b1[j] = f2b(h0[n + j]); c2[j] = c0[n + j];
  }
  if (i < NB2 * 16) barmem[i] = 0u;
}

// ---- tin GEMM, 128x128 tile, reg-staged swizzled LDS, 4 waves ----
// Ct[t][col][batch] (bf16) = A[M][1024](bf16) @ BT[col][1024]^T + bias
__global__ __launch_bounds__(256, 3) void k_gemm_t2(
    const ushort* __restrict__ A, const ushort* __restrict__ BT,
    const float* __restrict__ bias, ushort* __restrict__ Ct, int M) {
  __shared__ ushort As[128 * 64];
  __shared__ ushort Bs[128 * 64];
  const int tid = threadIdx.x;
  const int lane = tid & 63;
  const int w = tid >> 6;
  const int n0 = blockIdx.x * 128;
  const int m0 = blockIdx.y * 128;
  const int l15 = lane & 15;
  const int lg = lane >> 4;
  const int srow = tid >> 3;          // staging row (+ i*32)
  const int scol = (tid & 7) * 8;     // staging col (elements)
  const int wr = w >> 1, wc = w & 1;

  f32x4 acc[4][4] = {};

  for (int kt = 0; kt < 1024; kt += 64) {
    u32x4 av[4], bvv[4];
    #pragma unroll
    for (int i = 0; i < 4; ++i) {
      int row = srow + i * 32;
      av[i] = *(const u32x4*)(A + (size_t)(m0 + row) * 1024 + kt + scol);
      int brow = n0 + row; if (brow >= GSZ) brow = GSZ - 1;
      bvv[i] = *(const u32x4*)(BT + (size_t)brow * 1024 + kt + scol);
    }
    __syncthreads();  // previous iteration's LDS reads complete
    #pragma unroll
    for (int i = 0; i < 4; ++i) {
      int row = srow + i * 32;
      unsigned L = (unsigned)row * 128u + (unsigned)scol * 2u;
      unsigned Ls = L ^ ((unsigned)(row & 7) << 4);
      *(u32x4*)((char*)As + Ls) = av[i];
      *(u32x4*)((char*)Bs + Ls) = bvv[i];
    }
    __syncthreads();
    #pragma unroll
    for (int kk = 0; kk < 2; ++kk) {
      bf16x8 af[4], bf[4];
      #pragma unroll
      for (int i = 0; i < 4; ++i) {
        int arow = wr * 64 + i * 16 + l15;
        unsigned L = (unsigned)arow * 128u + (unsigned)kk * 64u + (unsigned)lg * 16u;
        af[i] = *(const bf16x8*)((const char*)As + (L ^ ((unsigned)(arow & 7) << 4)));
        int bcol = wc * 64 + i * 16 + l15;
        unsigned Lb = (unsigned)bcol * 128u + (unsigned)kk * 64u + (unsigned)lg * 16u;
        bf[i] = *(const bf16x8*)((const char*)Bs + (Lb ^ ((unsigned)(bcol & 7) << 4)));
      }
      #pragma unroll
      for (int i = 0; i < 4; ++i)
        #pragma unroll
        for (int j = 0; j < 4; ++j)
          acc[i][j] = __builtin_amdgcn_mfma_f32_16x16x32_bf16(af[i], bf[j], acc[i][j], 0, 0, 0);
    }
  }

  const int b4 = lg * 4;
  #pragma unroll
  for (int i = 0; i < 4; ++i) {
    int grow = m0 + wr * 64 + i * 16 + b4;  // global M row (4 consecutive)
    int t = grow >> 6;
    int b = grow & 63;
    #pragma unroll
    for (int j = 0; j < 4; ++j) {
      int col = n0 + wc * 64 + j * 16 + l15;
      if (col < GSZ) {
        float bb = bias[col];
        ushort4 o;
        o.x = f2b(acc[i][j][0] + bb); o.y = f2b(acc[i][j][1] + bb);
        o.z = f2b(acc[i][j][2] + bb); o.w = f2b(acc[i][j][3] + bb);
        *(ushort4*)(&Ct[((size_t)t * GSZ + col) * 64 + b]) = o;
      }
    }
  }
}

// ---- fused 2-layer persistent scan: 128 blocks x 1024 threads ----
// Round-12 structure, GEMM phase moved to 32x32x16 MFMA: 3 GEMM waves,
// wave = one 32-col tile (cols 0-31 sm+out, 32-63 cell+in, 64-95 fg+pad),
// each wave loads one B-frag per k-step (global/L2) reused for BOTH batch
// halves (2 acc chains) -> A-LDS reads drop 640->384 KB per pass.
__global__ __launch_bounds__(1024, 2) void k_scan2(
    const ushort* __restrict__ WhhT0, const ushort* __restrict__ WhhT1,
    const ushort* __restrict__ WihT1,
    const float* __restrict__ bhh0, const float* __restrict__ bhh1,
    const float* __restrict__ bih1,
    const ushort* __restrict__ tin,   // [nsteps][GSZ][64] bf16 (layer-0 only)
    ushort* __restrict__ h1b0, ushort* __restrict__ h1b1,
    ushort* __restrict__ h2b0, ushort* __restrict__ h2b1,
    float* __restrict__ c1, float* __restrict__ c2,
    float* __restrict__ outs0, float* __restrict__ outs1,
    float* __restrict__ outdup,
    float* __restrict__ dfs0, float* __restrict__ dins0,
    float* __restrict__ dfs1, float* __restrict__ dins1,
    float* __restrict__ hT0, float* __restrict__ cT0,
    float* __restrict__ hT1, float* __restrict__ cT1,
    unsigned* __restrict__ barmem, int nsteps, int t0, int barbase) {
  __shared__ unsigned hlds[32768];              // 128 KB, XOR-swizzled h
  __shared__ __align__(16) float gbuf[96][68];  // [gate col][batch]

  const int tid = threadIdx.x;
  const int blk = blockIdx.x;
  const bool isL2 = blk >= 64;
  const int lblk = isL2 ? (blk - 64) : blk;
  const int j0 = lblk * 16;
  const int lane = tid & 63;
  const int w = tid >> 6;       // wave 0..15
  const int l31 = lane & 31;
  const int khalf = lane >> 5;  // 0..1 (k-slot)

  // 32x32 GEMM constants (waves 0..2, one 32-col tile each, both batch halves)
  const int gc_ = (w < 3 ? w : 0) * 32 + l31;   // gbuf col 0..95
  int gcol32;
  if (gc_ < 16)      gcol32 = gc_;
  else if (gc_ < 80) gcol32 = 16 + ((gc_ - 16) >> 4) * 1024 + j0 + ((gc_ - 16) & 15);
  else               gcol32 = 16 + 3 * 1024 + j0 + (gc_ - 80);  // pad: dup fg
  const ushort* bp32A = (isL2 ? WhhT1 : WhhT0) + (size_t)gcol32 * HID + khalf * 8;
  const ushort* bp32B = WihT1 + (size_t)gcol32 * HID + khalf * 8;
  const float bv32 = isL2 ? (bhh1[gcol32] + bih1[gcol32]) : bhh0[gcol32];
  // A-frag LDS offsets: rows bg*32 + l31, k byte = ks*32 + khalf*16
  const unsigned a0base = (unsigned)l31 * 2048u + (unsigned)khalf * 16u;
  const unsigned a1base = a0base + 32u * 2048u;
  const unsigned swz32 = (unsigned)(l31 & 7) << 4;

  // cell mapping
  const int cb = tid >> 4;
  const int jl = tid & 15;
  const int jglob = j0 + jl;
  const int rch = jglob >> 7;
  float creg = (isL2 ? c2 : c1)[cb * HID + jglob];

  float* out_my  = isL2 ? outs1 : outs0;
  float* dfs_my  = isL2 ? dfs1  : dfs0;
  float* dins_my = isL2 ? dins1 : dins0;

  float def_hy = 0.f, def_df = 0.f, def_di = 0.f;
  size_t def_oidx = 0;
  int def_didx = 0;
  bool have_def = false;

#define LOAD8(hbase) do { \
    const u32x4* hs_ = (const u32x4*)(hbase); \
    asm volatile("global_load_dwordx4 %0, %1, off sc0 sc1" : "=v"(z0) : "v"(hs_ + tid)        : "memory"); \
    asm volatile("global_load_dwordx4 %0, %1, off sc0 sc1" : "=v"(z1) : "v"(hs_ + tid + 1024) : "memory"); \
    asm volatile("global_load_dwordx4 %0, %1, off sc0 sc1" : "=v"(z2) : "v"(hs_ + tid + 2048) : "memory"); \
    asm volatile("global_load_dwordx4 %0, %1, off sc0 sc1" : "=v"(z3) : "v"(hs_ + tid + 3072) : "memory"); \
    asm volatile("global_load_dwordx4 %0, %1, off sc0 sc1" : "=v"(z4) : "v"(hs_ + tid + 4096) : "memory"); \
    asm volatile("global_load_dwordx4 %0, %1, off sc0 sc1" : "=v"(z5) : "v"(hs_ + tid + 5120) : "memory"); \
    asm volatile("global_load_dwordx4 %0, %1, off sc0 sc1" : "=v"(z6) : "v"(hs_ + tid + 6144) : "memory"); \
    asm volatile("global_load_dwordx4 %0, %1, off sc0 sc1" : "=v"(z7) : "v"(hs_ + tid + 7168) : "memory"); \
  } while (0)

#define WRITE8() do { \
    unsigned b_; \
    b_ = (unsigned)tid * 16u;          *(u32x4*)((char*)hlds + (b_ ^ (((b_ >> 11) & 7u) << 4))) = z0; \
    b_ = (unsigned)(tid + 1024) * 16u; *(u32x4*)((char*)hlds + (b_ ^ (((b_ >> 11) & 7u) << 4))) = z1; \
    b_ = (unsigned)(tid + 2048) * 16u; *(u32x4*)((char*)hlds + (b_ ^ (((b_ >> 11) & 7u) << 4))) = z2; \
    b_ = (unsigned)(tid + 3072) * 16u; *(u32x4*)((char*)hlds + (b_ ^ (((b_ >> 11) & 7u) << 4))) = z3; \
    b_ = (unsigned)(tid + 4096) * 16u; *(u32x4*)((char*)hlds + (b_ ^ (((b_ >> 11) & 7u) << 4))) = z4; \
    b_ = (unsigned)(tid + 5120) * 16u; *(u32x4*)((char*)hlds + (b_ ^ (((b_ >> 11) & 7u) << 4))) = z5; \
    b_ = (unsigned)(tid + 6144) * 16u; *(u32x4*)((char*)hlds + (b_ ^ (((b_ >> 11) & 7u) << 4))) = z6; \
    b_ = (unsigned)(tid + 7168) * 16u; *(u32x4*)((char*)hlds + (b_ ^ (((b_ >> 11) & 7u) << 4))) = z7; \
  } while (0)

#define GEMM32(bp) do { \
    _Pragma("unroll 8") \
    for (int ks = 0; ks < 64; ++ks) { \
      bf16x8 b_ = *(const bf16x8*)((bp) + ks * 16); \
      bf16x8 xA = *(const bf16x8*)((const char*)hlds + ((a0base + (unsigned)ks * 32u) ^ swz32)); \
      bf16x8 xB = *(const bf16x8*)((const char*)hlds + ((a1base + (unsigned)ks * 32u) ^ swz32)); \
      accA = __builtin_amdgcn_mfma_f32_32x32x16_bf16(xA, b_, accA, 0, 0, 0); \
      accB = __builtin_amdgcn_mfma_f32_32x32x16_bf16(xB, b_, accB, 0, 0, 0); \
    } \
  } while (0)

// epilogue: C/D layout col=lane&31, row=(reg&3)+8*(reg>>2)+4*(lane>>5)
#define EPI_TILE(accX, bg, TQ) do { \
    _Pragma("unroll") \
    for (int q = 0; q < 4; ++q) { \
      int rb = (bg) * 32 + q * 8 + khalf * 4; \
      f32x4 g; \
      g[0] = accX[q * 4 + 0] + bv32 TQ(q, 0); \
      g[1] = accX[q * 4 + 1] + bv32 TQ(q, 1); \
      g[2] = accX[q * 4 + 2] + bv32 TQ(q, 2); \
      g[3] = accX[q * 4 + 3] + bv32 TQ(q, 3); \
      *(f32x4*)(&gbuf[gc_][rb]) = g; \
    } \
  } while (0)

  for (int r = 0; r <= nsteps; ++r) {
    // flush deferred outputs from the previous round (nt stores)
    if (have_def) {
      asm volatile("global_store_dword %0, %1, off nt"
                   :: "v"(&out_my[def_oidx]), "v"(def_hy) : "memory");
      if (isL2)
        asm volatile("global_store_dword %0, %1, off nt"
                     :: "v"(&outdup[def_oidx]), "v"(def_hy) : "memory");
      if (lblk == 0 && jl == 0) {
        dfs_my[def_didx] = def_df;
        dins_my[def_didx] = def_di;
      }
      have_def = false;
    }

    const bool active = isL2 ? (r >= 1) : (r < nsteps);
    if (active) {
      const int t = isL2 ? (t0 + r - 1) : (t0 + r);
      const int tloc = isL2 ? (r - 1) : r;

      if (!isL2) {
        // layer 0: stage h0(t-1), 32x32 GEMM vs Whh0, tin (nt) epilogue
        u32x4 z0, z1, z2, z3, z4, z5, z6, z7;
        LOAD8(((t - 1) & 1) ? h1b1 : h1b0);
        asm volatile("s_waitcnt vmcnt(0)" ::: "memory");
        __builtin_amdgcn_sched_barrier(0);
        WRITE8();
        __syncthreads();
        if (w < 3) {
          const ushort* tp = tin + ((size_t)tloc * GSZ + gcol32) * 64 + khalf * 4;
          u32x2 tq[8];
          #pragma unroll
          for (int q = 0; q < 8; ++q)
            asm volatile("global_load_dwordx2 %0, %1, off nt"
                         : "=v"(tq[q]) : "v"(tp + (q & 3) * 8 + (q >> 2) * 32) : "memory");
          f32x16 accA = {}, accB = {};
          GEMM32(bp32A);
          asm volatile("s_waitcnt vmcnt(0)" ::: "memory");
          __builtin_amdgcn_sched_barrier(0);
          ushort4 tu[8];
          #pragma unroll
          for (int q = 0; q < 8; ++q) *(u32x2*)&tu[q] = tq[q];
#define TQA(q, ii) + b2f((&tu[q].x)[ii])
#define TQB(q, ii) + b2f((&tu[4 + q].x)[ii])
          EPI_TILE(accA, 0, TQA);
          EPI_TILE(accB, 1, TQB);
#undef TQA
#undef TQB
        }
        __syncthreads();
      } else {
        // layer 1: pass A = h1(t-1)@Whh1 (pass-B h loads in flight), then
        // pass B = h0(t)@Wih1 accumulating into the same accs.
        f32x16 accA = {}, accB = {};
        {
          u32x4 z0, z1, z2, z3, z4, z5, z6, z7;
          LOAD8(((t - 1) & 1) ? h2b1 : h2b0);
          asm volatile("s_waitcnt vmcnt(0)" ::: "memory");
          __builtin_amdgcn_sched_barrier(0);
          WRITE8();
          __syncthreads();
        }
        {
          u32x4 z0, z1, z2, z3, z4, z5, z6, z7;
          LOAD8((t & 1) ? h1b1 : h1b0);   // completes under pass A
          if (w < 3) GEMM32(bp32A);
          asm volatile("s_waitcnt vmcnt(0)" ::: "memory");
          __builtin_amdgcn_sched_barrier(0);
          __syncthreads();                 // pass-A hlds reads complete
          WRITE8();
          __syncthreads();
        }
        if (w < 3) {
          GEMM32(bp32B);
#define TQN(q, ii)
          EPI_TILE(accA, 0, TQN);
          EPI_TILE(accB, 1, TQN);
#undef TQN
        }
        __syncthreads();
      }

      // ---- fused cell update ----
      float sm0[NCH], sm1[NCH];
      float m1 = -1e30f, m2 = -1e30f;
      #pragma unroll
      for (int i = 0; i < NCH; ++i) {
        sm0[i] = gbuf[i][cb];
        sm1[i] = gbuf[NCH + i][cb];
        m1 = fmaxf(m1, sm0[i]);
        m2 = fmaxf(m2, sm1[i]);
      }
      float s1 = 0.f, s2 = 0.f;
      #pragma unroll
      for (int i = 0; i < NCH; ++i) {
        sm0[i] = expf(sm0[i] - m1); s1 += sm0[i];
        sm1[i] = expf(sm1[i] - m2); s2 += sm1[i];
      }
      float r1 = 1.f / s1, r2 = 1.f / s2;
      float cum1 = 0.f, cum2 = 0.f, sumin = 0.f, sumfg = 0.f;
      float cing[NCH], cfg[NCH];
      #pragma unroll
      for (int i = 0; i < NCH; ++i) {
        cum1 += sm0[i] * r1; cing[i] = 1.f - cum1; sumin += cing[i];
        cum2 += sm1[i] * r2; cfg[i] = cum2; sumfg += cfg[i];
      }
      float go = gbuf[16 + jl][cb];
      float gc = gbuf[32 + jl][cb];
      float gi = gbuf[48 + jl][cb];
      float gf = gbuf[64 + jl][cb];
      float ov = cfg[rch] * cing[rch];
      float f_ = sigmoidf(gf) * ov + (cfg[rch] - ov);
      float i_ = sigmoidf(gi) * ov + (cing[rch] - ov);
      float cy = f_ * creg + i_ * tanhf(gc);
      float hy = sigmoidf(go) * tanhf(cy);
      creg = cy;

      // h store: write-through to LLC, packed bf16 pairs
      ushort hv = f2b(hy);
      unsigned other = (unsigned)__shfl_xor((int)(unsigned)hv, 1, 64);
      ushort* ring = isL2 ? ((t & 1) ? h2b1 : h2b0) : ((t & 1) ? h1b1 : h1b0);
      ushort* hw = ring + cb * HID + jglob;
      if ((jl & 1) == 0) {
        unsigned pk = (unsigned)hv | (other << 16);
        asm volatile("global_store_dword %0, %1, off sc0 sc1" :: "v"(hw), "v"(pk) : "memory");
      }
      if (!isL2 && hT0 && r == nsteps - 1) {
        hT0[cb * HID + jglob] = hy; cT0[cb * HID + jglob] = cy;
      }
      if (isL2 && hT1 && r == nsteps) {
        hT1[cb * HID + jglob] = hy; cT1[cb * HID + jglob] = cy;
      }

      def_hy = hy;
      def_oidx = ((size_t)tloc * BATCH + cb) * HID + jglob;
      def_didx = tloc * BATCH + cb;
      def_df = 1.f - sumfg * 0.125f;
      def_di = sumin * 0.125f;
      have_def = true;
    }

    // ---- global flag barrier over 128 blocks ----
    if (r < nsteps) {
      asm volatile("s_waitcnt vmcnt(0)" ::: "memory");  // h store at LLC
      __syncthreads();
      if (w == 0) {
        unsigned tgt = (unsigned)(barbase + r + 1);
        if (lane == 0) {
          unsigned* fp = barmem + (unsigned)blk * 16u;
          asm volatile("global_store_dword %0, %1, off sc0 sc1"
                       :: "v"(fp), "v"(tgt) : "memory");
        }
        const unsigned* mp0 = barmem + (unsigned)lane * 16u;
        const unsigned* mp1 = barmem + (unsigned)(64 + lane) * 16u;
        while (true) {
          unsigned f0, f1;
          asm volatile("global_load_dword %0, %1, off sc0 sc1"
                       : "=v"(f0) : "v"(mp0) : "memory");
          asm volatile("global_load_dword %0, %1, off sc0 sc1"
                       : "=v"(f1) : "v"(mp1) : "memory");
          asm volatile("s_waitcnt vmcnt(0)" ::: "memory");
          if (__all((int)(f0 >= tgt && f1 >= tgt))) break;
        }
      }
      __syncthreads();
    }
  }

  // final deferred flush (layer-1 role's last step)
  if (have_def) {
    out_my[def_oidx] = def_hy;
    if (isL2) outdup[def_oidx] = def_hy;
    if (lblk == 0 && jl == 0) {
      dfs_my[def_didx] = def_df;
      dins_my[def_didx] = def_di;
    }
  }
  (isL2 ? c2 : c1)[cb * HID + jglob] = creg;
#undef LOAD8
#undef WRITE8
#undef GEMM32
#undef EPI_TILE
}

extern "C" void kernel_launch(void* const* d_in, const int* in_sizes, int n_in,
                              void* d_out, int out_size, void* d_ws, size_t ws_size,
                              hipStream_t stream) {
  const float* x   = (const float*)d_in[0];
  const float* h0  = (const float*)d_in[1];
  const float* c0  = (const float*)d_in[2];
  const float* Wih = (const float*)d_in[3];
  const float* bih = (const float*)d_in[4];
  const float* Whh = (const float*)d_in[5];
  const float* bhh = (const float*)d_in[6];
  float* out = (float*)d_out;

  const size_t OFF_OUTPUT = 0;                  // (512,64,1024)
  const size_t OFF_HT   = 33554432;             // (2,64,1024)
  const size_t OFF_CT   = OFF_HT + 131072;      // (2,64,8,128)
  const size_t OFF_OUTS = OFF_CT + 131072;      // (2,512,64,1024)
  const size_t OFF_DFS  = OFF_OUTS + 67108864;  // (2,512,64)
  const size_t OFF_DINS = OFF_DFS + 65536;      // (2,512,64)

  uint8_t* ws = (uint8_t*)d_ws;
  size_t off = 0;
  auto alloc = [&](size_t bytes) { size_t p = off; off = (off + bytes + 255) & ~(size_t)255; return p; };
  const size_t wT_sz = (size_t)GSZ * HID * 2;
  size_t o_WihT[2], o_WhhT[2];
  o_WihT[0] = alloc(wT_sz); o_WihT[1] = alloc(wT_sz);
  o_WhhT[0] = alloc(wT_sz); o_WhhT[1] = alloc(wT_sz);
  size_t o_h1b0 = alloc((size_t)BATCH * HID * 2);
  size_t o_h1b1 = alloc((size_t)BATCH * HID * 2);
  size_t o_h2b0 = alloc((size_t)BATCH * HID * 2);
  size_t o_h2b1 = alloc((size_t)BATCH * HID * 2);
  size_t o_c1   = alloc((size_t)BATCH * HID * 4);
  size_t o_c2   = alloc((size_t)BATCH * HID * 4);
  size_t o_bar  = alloc(NB2 * 16 * 4);
  size_t fixed = off;
  const size_t unit = (size_t)BATCH * HID * 2 + (size_t)BATCH * GSZ * 2 + 512;
  int TC = 256;
  while (TC > 2 && fixed + (size_t)TC * unit > ws_size) TC >>= 1;
  size_t o_prevb = alloc((size_t)TC * BATCH * HID * 2);
  size_t o_tin   = alloc((size_t)TC * BATCH * GSZ * 2);

  ushort* h1b0 = (ushort*)(ws + o_h1b0);
  ushort* h1b1 = (ushort*)(ws + o_h1b1);
  ushort* h2b0 = (ushort*)(ws + o_h2b0);
  ushort* h2b1 = (ushort*)(ws + o_h2b1);
  float*  c1   = (float*)(ws + o_c1);
  float*  c2   = (float*)(ws + o_c2);
  unsigned* barmem = (unsigned*)(ws + o_bar);
  ushort* prevb = (ushort*)(ws + o_prevb);
  ushort* tin   = (ushort*)(ws + o_tin);

  // weight transposes (bf16, [GSZ][HID])
  dim3 tgrid((GSZ + 31) / 32, HID / 32);
  for (int l = 0; l < 2; ++l) {
    k_transpose_cast<<<tgrid, 256, 0, stream>>>(Wih + (size_t)l * HID * GSZ,
                                                (ushort*)(ws + o_WihT[l]), HID, GSZ);
    k_transpose_cast<<<tgrid, 256, 0, stream>>>(Whh + (size_t)l * HID * GSZ,
                                                (ushort*)(ws + o_WhhT[l]), HID, GSZ);
  }

  k_init2<<<(2 * BATCH * HID + 255) / 256, 256, 0, stream>>>(
      h0, c0, h1b1, h2b1, c1, c2, barmem);

  int barbase = 0;
  for (int t0 = 0; t0 < LSEQ; t0 += TC) {
    int nsteps = (LSEQ - t0 < TC) ? (LSEQ - t0) : TC;

    // layer-0 tin for this chunk (x only — independent of the scan)
    int count4 = nsteps * BATCH * HID / 4;
    int cblocks = (count4 + 255) / 256; if (cblocks > 2048) cblocks = 2048;
    k_cast4<<<cblocks, 256, 0, stream>>>(
        (const float4*)(x + (size_t)t0 * BATCH * HID), prevb, count4);
    int M = nsteps * 64;
    k_gemm_t2<<<dim3((GSZ + 127) / 128, M / 128), 256, 0, stream>>>(
        prevb, (const ushort*)(ws + o_WihT[0]), bih, tin, M);

    bool last = (t0 + nsteps == LSEQ);
    const ushort* WhhT0_p = (const ushort*)(ws + o_WhhT[0]);
    const ushort* WhhT1_p = (const ushort*)(ws + o_WhhT[1]);
    const ushort* WihT1_p = (const ushort*)(ws + o_WihT[1]);
    const float* bhh0_p = bhh;
    const float* bhh1_p = bhh + GSZ;
    const float* bih1_p = bih + GSZ;
    const ushort* tin_p = tin;
    float* outs0 = out + OFF_OUTS + (size_t)t0 * BATCH * HID;
    float* outs1 = out + OFF_OUTS + ((size_t)LSEQ + t0) * BATCH * HID;
    float* outdup = out + OFF_OUTPUT + (size_t)t0 * BATCH * HID;
    float* dfs0  = out + OFF_DFS  + (size_t)t0 * BATCH;
    float* dins0 = out + OFF_DINS + (size_t)t0 * BATCH;
    float* dfs1  = out + OFF_DFS  + ((size_t)LSEQ + t0) * BATCH;
    float* dins1 = out + OFF_DINS + ((size_t)LSEQ + t0) * BATCH;
    float* hT0 = last ? (out + OFF_HT) : nullptr;
    float* cT0 = last ? (out + OFF_CT) : nullptr;
    float* hT1 = last ? (out + OFF_HT + (size_t)BATCH * HID) : nullptr;
    float* cT1 = last ? (out + OFF_CT + (size_t)BATCH * HID) : nullptr;
    int nsteps_v = nsteps;
    int t0_v = t0;
    int barbase_v = barbase;

    void* args[] = {&WhhT0_p, &WhhT1_p, &WihT1_p, &bhh0_p, &bhh1_p, &bih1_p,
                    &tin_p, &h1b0, &h1b1, &h2b0, &h2b1, &c1, &c2,
                    &outs0, &outs1, &outdup, &dfs0, &dins0, &dfs1, &dins1,
                    &hT0, &cT0, &hT1, &cT1, &barmem, &nsteps_v, &t0_v, &barbase_v};
    hipLaunchCooperativeKernel((const void*)k_scan2, dim3(NB2), dim3(1024),
                               args, 0, stream);
    barbase += nsteps;
  }
}